// Round 8
// baseline (335.440 us; speedup 1.0000x reference)
//
#include <hip/hip_runtime.h>

// ---------------------------------------------------------------------------
// Refine_moduleGNN: pad+transpose -> DENSE even-grid conv (gemm3 body) ->
// scatter -> pre-MLP -> 2x EdgeConv -> head. MFMA bf16 throughout.
// R3 best = 265us (gather conv). R6/R7 CHW-staged dense conv failed
// (latency-serial cross-channel staging). R8: dense conv from channel-last
// imgT using the VERIFIED conv_gather_gemm3 body with dense row mapping.
// ---------------------------------------------------------------------------

typedef __bf16 bf16_t;
typedef bf16_t bf16x2 __attribute__((ext_vector_type(2)));
typedef bf16_t bf16x8 __attribute__((ext_vector_type(8)));
typedef float  f32x4  __attribute__((ext_vector_type(4)));

static constexpr int BATCH = 16;
static constexpr int NPT   = 512;
static constexpr int PTS   = BATCH * NPT;   // 8192

// padded image dims (+4 origin)
static constexpr int PY_DIM = 136;
static constexpr size_t IMG_BSTRIDE = (size_t)PY_DIM * PY_DIM * 256;

// dense conv output: yo,xs in [0,66), stored with xs-stride 80
static constexpr int YO = 66, XSP = 80, OC = 64;

// ---- workspace layout (bytes) ----
static constexpr size_t OFF_WCONVP = 0;                                  // [64][16][256]
static constexpr size_t OFF_WPRE1  = OFF_WCONVP + (size_t)64*4096*2;
static constexpr size_t OFF_WPRE2  = OFF_WPRE1  + (size_t)256*320*2;
static constexpr size_t OFF_WEC1   = OFF_WPRE2  + (size_t)256*256*2;
static constexpr size_t OFF_WEC2   = OFF_WEC1   + (size_t)512*256*2;
static constexpr size_t OFF_WQ1    = OFF_WEC2   + (size_t)512*256*2;
static constexpr size_t OFF_WQ2    = OFF_WQ1    + (size_t)256*256*2;
static constexpr size_t OFF_LOCAL  = OFF_WQ2    + (size_t)64*256*2;      // [8192][320]
static constexpr size_t OFF_X      = OFF_LOCAL  + (size_t)PTS*320*2;
static constexpr size_t OFF_Y      = OFF_X      + (size_t)PTS*256*2;
static constexpr size_t OFF_Z      = OFF_Y      + (size_t)PTS*256*2;     // [8192][64]
// union: AB f32 (16MB, edgeconv) | Oconv bf16 (10.8MB, conv phase)
static constexpr size_t OFF_UNION  = OFF_Z      + (size_t)PTS*64*2;
static constexpr size_t AB_BYTES   = (size_t)PTS*512*4;                  // 16 MB
static constexpr size_t OFF_IMGT   = OFF_UNION  + AB_BYTES;
static constexpr size_t IMGT_BYTES = (size_t)16*IMG_BSTRIDE*2;           // ~151 MB
static constexpr size_t WS_NEEDED  = OFF_IMGT + IMGT_BYTES;              // ~185 MB

// ---------------------------------------------------------------------------
// Weight prep
// ---------------------------------------------------------------------------
static constexpr int WP_CONVP = 64*4096;
static constexpr int WP_PRE1 = 256*320;
static constexpr int WP_PRE2 = 256*256;
static constexpr int WP_EC   = 512*256;
static constexpr int WP_Q1   = 256*256;
static constexpr int WP_Q2   = 64*256;
static constexpr int WP_TOTAL = WP_CONVP + WP_PRE1 + WP_PRE2 + 2*WP_EC + WP_Q1 + WP_Q2;

__global__ __launch_bounds__(256) void wprep_kernel(
    const float* __restrict__ conv_w, const float* __restrict__ pre_w1,
    const float* __restrict__ pre_w2, const float* __restrict__ g1_w,
    const float* __restrict__ g2_w,   const float* __restrict__ q_w1,
    const float* __restrict__ q_w2,
    bf16_t* __restrict__ wt_convp, bf16_t* __restrict__ wt_pre1,
    bf16_t* __restrict__ wt_pre2,  bf16_t* __restrict__ wt_ec1,
    bf16_t* __restrict__ wt_ec2,   bf16_t* __restrict__ wt_q1,
    bf16_t* __restrict__ wt_q2)
{
    int i = blockIdx.x * 256 + threadIdx.x;
    if (i >= WP_TOTAL) return;
    if (i < WP_CONVP) {   // [o][pix][c] <- conv_w[(o*256+c)*16 + pix]
        const int o = i >> 12, pix = (i >> 8) & 15, c = i & 255;
        wt_convp[i] = (bf16_t)conv_w[((o * 256 + c) << 4) + pix]; return; }
    i -= WP_CONVP;
    if (i < WP_PRE1) { int n = i / 320, k = i - n * 320;
        wt_pre1[i] = (bf16_t)pre_w1[k * 256 + n]; return; }
    i -= WP_PRE1;
    if (i < WP_PRE2) { int n = i >> 8, k = i & 255;
        wt_pre2[i] = (bf16_t)pre_w2[k * 256 + n]; return; }
    i -= WP_PRE2;
    if (i < WP_EC) { int n = i >> 8, k = i & 255;
        wt_ec1[i] = (bf16_t)(n < 256 ? g1_w[n * 512 + k] : g1_w[(n - 256) * 512 + 256 + k]);
        return; }
    i -= WP_EC;
    if (i < WP_EC) { int n = i >> 8, k = i & 255;
        wt_ec2[i] = (bf16_t)(n < 256 ? g2_w[n * 512 + k] : g2_w[(n - 256) * 512 + 256 + k]);
        return; }
    i -= WP_EC;
    if (i < WP_Q1) { int n = i >> 8, k = i & 255;
        wt_q1[i] = (bf16_t)q_w1[k * 256 + n]; return; }
    i -= WP_Q1;
    { int n = i >> 8, k = i & 255;
        wt_q2[i] = (bf16_t)q_w2[k * 64 + n]; }
}

// ---------------------------------------------------------------------------
// Border zero for padded imgT (verified R2)
// ---------------------------------------------------------------------------
static constexpr int PAD_THREADS = 16 * 2112 * 32;

__global__ __launch_bounds__(256) void pad_border(bf16_t* __restrict__ imgT)
{
    const int idx = blockIdx.x * 256 + threadIdx.x;
    if (idx >= PAD_THREADS) return;
    const int t = idx & 31;
    int pi = idx >> 5;
    const int b = pi / 2112; pi -= b * 2112;
    int y, x;
    if (pi < 544)      { y = pi / 136;              x = pi % 136; }
    else if (pi < 1088){ int j = pi - 544; y = 132 + j / 136; x = j % 136; }
    else { int j = pi - 1088; y = 4 + (j >> 3); int k = j & 7; x = (k < 4) ? k : (128 + k); }
    const uint4 z = {0, 0, 0, 0};
    ((uint4*)(imgT + ((size_t)(b * PY_DIM + y) * PY_DIM + x) * 256))[t] = z;
}

// ---------------------------------------------------------------------------
// Image transpose: img[b][c][y][x] f32 -> imgT[b][y+4][x+4][c] bf16 (verified)
// ---------------------------------------------------------------------------
__global__ __launch_bounds__(256) void transpose_img(
    const float* __restrict__ img, bf16_t* __restrict__ imgT)
{
    __shared__ float T[64][65];
    const int bid = blockIdx.x;
    const int cc = bid & 3;
    const int xh = (bid >> 2) & 1;
    const int y  = (bid >> 3) & 127;
    const int b  = bid >> 10;
    const int t = threadIdx.x;
    const int x0 = xh * 64, c0 = cc * 64;
    {
        const int px = t & 63, cr = t >> 6;
        const float* src = img + ((size_t)(b * 256 + c0 + cr) * 128 + y) * 128 + x0 + px;
        #pragma unroll
        for (int i = 0; i < 16; ++i)
            T[cr + i * 4][px] = src[(size_t)i * 4 * 16384];
    }
    __syncthreads();
    {
        const int cl2 = (t & 31) * 2, pr = t >> 5;
        bf16_t* dst = imgT + ((size_t)(b * PY_DIM + y + 4) * PY_DIM + x0 + 4) * 256 + c0 + cl2;
        #pragma unroll
        for (int i = 0; i < 8; ++i) {
            const int pxl = pr + i * 8;
            bf16x2 w;
            w[0] = (bf16_t)T[cl2][pxl];
            w[1] = (bf16_t)T[cl2 + 1][pxl];
            *(bf16x2*)(dst + (size_t)pxl * 256) = w;
        }
    }
}

// ---------------------------------------------------------------------------
// Dense conv from imgT: exact conv_gather_gemm3 body (verified), dense rows.
// Block = (b, typ<33, txs<5): rows = 2 yo x 16 xs (xs clamped to 65).
// Row r: yo = 2*typ + (r>>4), xs = min(16*txs + (r&15), 65);
// padded coords oy = 2*yo+1, ox = 2*xs+1; K-step = (tap pix, ch-half).
// ---------------------------------------------------------------------------
__global__ __launch_bounds__(256) void conv_dense3(
    const bf16_t* __restrict__ imgT,    // [16][136][136][256]
    const bf16_t* __restrict__ Wc,      // [64][16][256]
    bf16_t* __restrict__ Oconv)         // [16][66][80][64]
{
    __shared__ bf16_t As[32][136];
    __shared__ bf16_t Bs[64][136];
    const int tid = threadIdx.x, lane = tid & 63, wave = tid >> 6;
    const int wm = wave & 1, wn = wave >> 1;
    const int bid = blockIdx.x;
    const int b = bid / 165;
    const int rem = bid - b * 165;
    const int typ = rem / 5, txs = rem - typ * 5;
    const int xs0 = txs * 16;

    // A staging: 32 rows x 8 segments (16 el each)
    const int ra = tid >> 3, seg = tid & 7;
    const int yo_r = 2 * typ + (ra >> 4);
    int xs_r = xs0 + (ra & 15); xs_r = xs_r < 66 ? xs_r : 65;
    const int oy = 2 * yo_r + 1;
    const int ox = 2 * xs_r + 1;
    const bf16_t* imgb = imgT + (size_t)b * IMG_BSTRIDE;
    // B staging: 64 rows x 4 segments
    const int rb = tid >> 2, sq = tid & 3;
    const bf16_t* wrow = Wc + (size_t)rb * 4096 + sq * 8;

    f32x4 acc[2] = {};
    #pragma unroll 1
    for (int s = 0; s < 32; ++s) {
        const int pix = s >> 1, h = s & 1;
        const int iy = oy + (pix >> 2), ix = ox + (pix & 3);
        {
            const bf16_t* srcA = imgb + ((size_t)(iy * PY_DIM + ix)) * 256 + h * 128 + seg * 16;
            *(uint4*)&As[ra][seg * 16]     = *(const uint4*)srcA;
            *(uint4*)&As[ra][seg * 16 + 8] = *(const uint4*)(srcA + 8);
        }
        {
            const bf16_t* srcB = wrow + pix * 256 + h * 128;
            #pragma unroll
            for (int i = 0; i < 4; ++i)
                *(uint4*)&Bs[rb][sq * 8 + i * 32] = *(const uint4*)(srcB + i * 32);
        }
        __syncthreads();
        #pragma unroll
        for (int kk = 0; kk < 128; kk += 32) {
            const int kf = kk + ((lane >> 4) << 3);
            bf16x8 a  = *(const bf16x8*)&As[wm * 16 + (lane & 15)][kf];
            bf16x8 b0 = *(const bf16x8*)&Bs[wn * 32 + (lane & 15)][kf];
            bf16x8 b1 = *(const bf16x8*)&Bs[wn * 32 + 16 + (lane & 15)][kf];
            acc[0] = __builtin_amdgcn_mfma_f32_16x16x32_bf16(a, b0, acc[0], 0, 0, 0);
            acc[1] = __builtin_amdgcn_mfma_f32_16x16x32_bf16(a, b1, acc[1], 0, 0, 0);
        }
        __syncthreads();
    }
    const int crow = (lane >> 4) << 2;
    const int ccol = lane & 15;
    #pragma unroll
    for (int j = 0; j < 2; ++j) {
        const int o = wn * 32 + j * 16 + ccol;
        #pragma unroll
        for (int rg = 0; rg < 4; ++rg) {
            const int m = wm * 16 + crow + rg;
            const int yo = 2 * typ + (m >> 4);
            int xs = xs0 + (m & 15); xs = xs < 66 ? xs : 65;
            // clamped duplicate rows write identical values -- benign
            Oconv[(((size_t)b * YO + yo) * XSP + xs) * OC + o] = (bf16_t)acc[j][rg];
        }
    }
}

// ---------------------------------------------------------------------------
// Scatter: local[p][cn*64+o] = (Oconv[b][py+2cy][px+2cx][o]+bias)*roi[p];
// + graph fold-in (verified R6 mapping, stride XSP).
// ---------------------------------------------------------------------------
__global__ __launch_bounds__(256) void scatter_local3(
    const bf16_t* __restrict__ Oconv, const float* __restrict__ conv_b,
    const float* __restrict__ roi,
    const int* __restrict__ px, const int* __restrict__ py,
    const float* __restrict__ graph,
    bf16_t* __restrict__ local)
{
    const int p = blockIdx.x;
    const int b = p >> 9, n = p & 511;
    const int t = threadIdx.x;
    const int corner = t >> 6, o = t & 63;
    const int yo = py[p] + ((corner & 1) << 1);
    const int xs = px[p] + (((corner >> 1) & 1) << 1);
    const float v = (float)Oconv[(((size_t)b * YO + yo) * XSP + xs) * OC + o] + conv_b[o];
    local[(size_t)p * 320 + t] = (bf16_t)(v * roi[p]);
    if (t < 64)
        local[(size_t)p * 320 + 256 + t] = (bf16_t)graph[((size_t)(b * 64 + t) << 9) + n];
}

// ---------------------------------------------------------------------------
// Generic MFMA GEMM: C[8192][N] = A[8192][K] @ Bt[N][K]^T (+bias, lrelu)
// ---------------------------------------------------------------------------
template<int K, int N, int ACT>
__global__ __launch_bounds__(256) void gemm_bf16(
    const bf16_t* __restrict__ A, const bf16_t* __restrict__ Bt,
    const float* __restrict__ bias, float slope,
    bf16_t* __restrict__ outB, float* __restrict__ outF)
{
    __shared__ bf16_t As[64][72];
    __shared__ bf16_t Bs[64][72];
    const int tid = threadIdx.x;
    const int lane = tid & 63;
    const int wave = tid >> 6;
    const int wm = wave & 1, wn = wave >> 1;
    const int row0 = blockIdx.x * 64;
    const int col0 = blockIdx.y * 64;
    const int sm = tid >> 2;
    const int sq = (tid & 3) << 4;

    f32x4 acc[2][2] = {};
    for (int kt = 0; kt < K; kt += 64) {
        {
            const bf16_t* src = A + (size_t)(row0 + sm) * K + kt + sq;
            *(uint4*)&As[sm][sq]     = *(const uint4*)src;
            *(uint4*)&As[sm][sq + 8] = *(const uint4*)(src + 8);
        }
        {
            const bf16_t* src = Bt + (size_t)(col0 + sm) * K + kt + sq;
            *(uint4*)&Bs[sm][sq]     = *(const uint4*)src;
            *(uint4*)&Bs[sm][sq + 8] = *(const uint4*)(src + 8);
        }
        __syncthreads();
        #pragma unroll
        for (int kk = 0; kk < 64; kk += 32) {
            const int kf = kk + ((lane >> 4) << 3);
            bf16x8 a0 = *(const bf16x8*)&As[wm * 32 + (lane & 15)][kf];
            bf16x8 a1 = *(const bf16x8*)&As[wm * 32 + 16 + (lane & 15)][kf];
            bf16x8 b0 = *(const bf16x8*)&Bs[wn * 32 + (lane & 15)][kf];
            bf16x8 b1 = *(const bf16x8*)&Bs[wn * 32 + 16 + (lane & 15)][kf];
            acc[0][0] = __builtin_amdgcn_mfma_f32_16x16x32_bf16(a0, b0, acc[0][0], 0, 0, 0);
            acc[0][1] = __builtin_amdgcn_mfma_f32_16x16x32_bf16(a0, b1, acc[0][1], 0, 0, 0);
            acc[1][0] = __builtin_amdgcn_mfma_f32_16x16x32_bf16(a1, b0, acc[1][0], 0, 0, 0);
            acc[1][1] = __builtin_amdgcn_mfma_f32_16x16x32_bf16(a1, b1, acc[1][1], 0, 0, 0);
        }
        __syncthreads();
    }
    const int crow = (lane >> 4) << 2;
    const int ccol = lane & 15;
    #pragma unroll
    for (int i = 0; i < 2; ++i) {
        #pragma unroll
        for (int j = 0; j < 2; ++j) {
            const int gcol = col0 + wn * 32 + j * 16 + ccol;
            const float bv = bias ? bias[gcol] : 0.0f;
            #pragma unroll
            for (int rg = 0; rg < 4; ++rg) {
                const int grow = row0 + wm * 32 + i * 16 + crow + rg;
                float v = acc[i][j][rg] + bv;
                if (ACT == 1) v = v >= 0.0f ? v : slope * v;
                if (outB) outB[(size_t)grow * N + gcol] = (bf16_t)v;
                if (outF) outF[(size_t)grow * N + gcol] = v;
            }
        }
    }
}

// ---------------------------------------------------------------------------
// EdgeConv combine
// ---------------------------------------------------------------------------
__global__ __launch_bounds__(256) void edge_combine(
    const float* __restrict__ AB, const int* __restrict__ knn,
    const float* __restrict__ gamma, const float* __restrict__ beta,
    const float* __restrict__ mean,  const float* __restrict__ var,
    bf16_t* __restrict__ outB, float* __restrict__ outT)
{
    const int p = blockIdx.x;
    const int b = p >> 9, n = p & 511;
    const int o = threadIdx.x;
    const float sc = gamma[o] / sqrtf(var[o] + 1e-5f);
    const float sh = beta[o] - mean[o] * sc;
    const float* rowp = AB + (size_t)p * 512;
    const float d = rowp[256 + o] - rowp[o];
    const float* batch = AB + ((size_t)(b << 9)) * 512;
    float m = -3.4e38f;
    #pragma unroll 4
    for (int k = 0; k < 20; ++k) {
        const int q = knn[n * 20 + k];
        const float v = batch[(size_t)q * 512 + o] + d;
        float y = v * sc + sh;
        y = y >= 0.0f ? y : 0.2f * y;
        m = fmaxf(m, y);
    }
    outB[(size_t)p * 256 + o] = (bf16_t)m;
    if (outT) outT[((size_t)(b * 256 + o) << 9) + n] = m;
}

// ---------------------------------------------------------------------------
// Head final layer
// ---------------------------------------------------------------------------
__global__ __launch_bounds__(256) void q3_kernel(
    const bf16_t* __restrict__ Z, const float* __restrict__ w3,
    const float* __restrict__ b3, float* __restrict__ out)
{
    const int p = blockIdx.x * 256 + threadIdx.x;
    const int b = p >> 9, n = p & 511;
    const bf16_t* q = Z + (size_t)p * 64;
    float s0 = b3[0], s1 = b3[1];
    #pragma unroll
    for (int c = 0; c < 64; ++c) {
        const float v = (float)q[c];
        s0 += v * w3[2 * c];
        s1 += v * w3[2 * c + 1];
    }
    out[(size_t)(b * 2 + 0) * 512 + n] = s0;
    out[(size_t)(b * 2 + 1) * 512 + n] = s1;
}

// ---------------------------------------------------------------------------
extern "C" void kernel_launch(void* const* d_in, const int* in_sizes, int n_in,
                              void* d_out, int out_size, void* d_ws, size_t ws_size,
                              hipStream_t stream)
{
    const float* img      = (const float*)d_in[0];
    const float* graph    = (const float*)d_in[1];
    const float* roi      = (const float*)d_in[2];
    const int*   px       = (const int*)d_in[3];
    const int*   py       = (const int*)d_in[4];
    const int*   knn      = (const int*)d_in[5];
    const float* conv_w   = (const float*)d_in[6];
    const float* conv_b   = (const float*)d_in[7];
    const float* pre_w1   = (const float*)d_in[8];
    const float* pre_b1   = (const float*)d_in[9];
    const float* pre_w2   = (const float*)d_in[10];
    const float* pre_b2   = (const float*)d_in[11];
    const float* g1_w     = (const float*)d_in[12];
    const float* g1_gamma = (const float*)d_in[13];
    const float* g1_beta  = (const float*)d_in[14];
    const float* g1_mean  = (const float*)d_in[15];
    const float* g1_var   = (const float*)d_in[16];
    const float* g2_w     = (const float*)d_in[17];
    const float* g2_gamma = (const float*)d_in[18];
    const float* g2_beta  = (const float*)d_in[19];
    const float* g2_mean  = (const float*)d_in[20];
    const float* g2_var   = (const float*)d_in[21];
    const float* q_w1     = (const float*)d_in[22];
    const float* q_b1     = (const float*)d_in[23];
    const float* q_w2     = (const float*)d_in[24];
    const float* q_b2     = (const float*)d_in[25];
    const float* q_w3     = (const float*)d_in[26];
    const float* q_b3     = (const float*)d_in[27];
    float* out = (float*)d_out;

    if (ws_size < WS_NEEDED) return;

    char* ws = (char*)d_ws;
    bf16_t* wt_convp = (bf16_t*)(ws + OFF_WCONVP);
    bf16_t* wt_pre1  = (bf16_t*)(ws + OFF_WPRE1);
    bf16_t* wt_pre2  = (bf16_t*)(ws + OFF_WPRE2);
    bf16_t* wt_ec1   = (bf16_t*)(ws + OFF_WEC1);
    bf16_t* wt_ec2   = (bf16_t*)(ws + OFF_WEC2);
    bf16_t* wt_q1    = (bf16_t*)(ws + OFF_WQ1);
    bf16_t* wt_q2    = (bf16_t*)(ws + OFF_WQ2);
    bf16_t* local    = (bf16_t*)(ws + OFF_LOCAL);
    bf16_t* X        = (bf16_t*)(ws + OFF_X);
    bf16_t* Y        = (bf16_t*)(ws + OFF_Y);
    bf16_t* Z        = (bf16_t*)(ws + OFF_Z);
    float*  AB       = (float*)(ws + OFF_UNION);
    bf16_t* Oconv    = (bf16_t*)(ws + OFF_UNION);   // union w/ AB (used first)
    bf16_t* imgT     = (bf16_t*)(ws + OFF_IMGT);

    wprep_kernel<<<(WP_TOTAL + 255) / 256, 256, 0, stream>>>(
        conv_w, pre_w1, pre_w2, g1_w, g2_w, q_w1, q_w2,
        wt_convp, wt_pre1, wt_pre2, wt_ec1, wt_ec2, wt_q1, wt_q2);

    pad_border<<<(PAD_THREADS + 255) / 256, 256, 0, stream>>>(imgT);
    transpose_img<<<16 * 128 * 2 * 4, 256, 0, stream>>>(img, imgT);
    conv_dense3<<<16 * 33 * 5, 256, 0, stream>>>(imgT, wt_convp, Oconv);
    scatter_local3<<<PTS, 256, 0, stream>>>(
        Oconv, conv_b, roi, px, py, graph, local);

    gemm_bf16<320, 256, 1><<<dim3(PTS / 64, 4), 256, 0, stream>>>(
        local, wt_pre1, pre_b1, 0.01f, X, nullptr);
    gemm_bf16<256, 256, 1><<<dim3(PTS / 64, 4), 256, 0, stream>>>(
        X, wt_pre2, pre_b2, 0.01f, Y, nullptr);

    gemm_bf16<256, 512, 0><<<dim3(PTS / 64, 8), 256, 0, stream>>>(
        Y, wt_ec1, nullptr, 0.0f, nullptr, AB);
    edge_combine<<<PTS, 256, 0, stream>>>(
        AB, knn, g1_gamma, g1_beta, g1_mean, g1_var, X, nullptr);

    gemm_bf16<256, 512, 0><<<dim3(PTS / 64, 8), 256, 0, stream>>>(
        X, wt_ec2, nullptr, 0.0f, nullptr, AB);
    edge_combine<<<PTS, 256, 0, stream>>>(
        AB, knn, g2_gamma, g2_beta, g2_mean, g2_var, Y, out + 16384);

    gemm_bf16<256, 256, 1><<<dim3(PTS / 64, 4), 256, 0, stream>>>(
        Y, wt_q1, q_b1, 0.01f, X, nullptr);
    gemm_bf16<256, 64, 1><<<dim3(PTS / 64, 1), 256, 0, stream>>>(
        X, wt_q2, q_b2, 0.01f, Z, nullptr);
    q3_kernel<<<PTS / 256, 256, 0, stream>>>(Z, q_w3, q_b3, out);
}

// Round 9
// 263.947 us; speedup vs baseline: 1.2709x; 1.2709x over previous
//
#include <hip/hip_runtime.h>

// ---------------------------------------------------------------------------
// Refine_moduleGNN: pad+transpose -> gather conv (v3) -> pre-MLP ->
// 2x EdgeConv -> head. MFMA bf16.
// R3 = 265us (best verified). R4-R8 experiments (sort, fusion, dense conv)
// all regressed and are reverted. R9 = exact R3 + bf16 AB (halves EdgeConv
// intermediate traffic).
// ---------------------------------------------------------------------------

typedef __bf16 bf16_t;
typedef bf16_t bf16x2 __attribute__((ext_vector_type(2)));
typedef bf16_t bf16x8 __attribute__((ext_vector_type(8)));
typedef float  f32x4  __attribute__((ext_vector_type(4)));

static constexpr int BATCH = 16;
static constexpr int NPT   = 512;
static constexpr int PTS   = BATCH * NPT;   // 8192
static constexpr int CONVM = PTS * 4;       // 32768 conv rows
static constexpr int CONVK = 4096;          // 256*4*4

// padded image dims (+4 origin)
static constexpr int PY_DIM = 136;
static constexpr size_t IMG_BSTRIDE = (size_t)PY_DIM * PY_DIM * 256;

// ---- workspace layout (bytes) ----
static constexpr size_t OFF_WCONV_OLD = 0;                                // [64][4096] (c,pix)
static constexpr size_t OFF_WCONVP    = OFF_WCONV_OLD + (size_t)64*4096*2;// [64][16][256]
static constexpr size_t OFF_WPRE1     = OFF_WCONVP    + (size_t)64*4096*2;
static constexpr size_t OFF_WPRE2     = OFF_WPRE1     + (size_t)256*320*2;
static constexpr size_t OFF_WEC1      = OFF_WPRE2     + (size_t)256*256*2;
static constexpr size_t OFF_WEC2      = OFF_WEC1      + (size_t)512*256*2;
static constexpr size_t OFF_WQ1       = OFF_WEC2      + (size_t)512*256*2;
static constexpr size_t OFF_WQ2       = OFF_WQ1       + (size_t)256*256*2;
static constexpr size_t OFF_LOCAL     = OFF_WQ2       + (size_t)64*256*2; // [8192][320] bf16
static constexpr size_t OFF_X         = OFF_LOCAL + (size_t)PTS*320*2;
static constexpr size_t OFF_Y         = OFF_X     + (size_t)PTS*256*2;
static constexpr size_t OFF_Z         = OFF_Y     + (size_t)PTS*256*2;    // [8192][64]
// union region: AB bf16 [8192][512] (edgeconv) | imgT (conv phase only)
static constexpr size_t OFF_UNION     = OFF_Z     + (size_t)PTS*64*2;
static constexpr size_t AB_BYTES      = (size_t)PTS*512*2;                 // 8 MB
static constexpr size_t IMGT_BYTES    = (size_t)16*IMG_BSTRIDE*2;          // ~145 MB
static constexpr size_t WS_BASE       = OFF_UNION + AB_BYTES;
static constexpr size_t WS_FULL       = OFF_UNION + IMGT_BYTES;

// ---------------------------------------------------------------------------
// Weight prep
// ---------------------------------------------------------------------------
static constexpr int WP_CONV  = 64*4096;
static constexpr int WP_CONVP = 64*4096;
static constexpr int WP_PRE1 = 256*320;
static constexpr int WP_PRE2 = 256*256;
static constexpr int WP_EC   = 512*256;
static constexpr int WP_Q1   = 256*256;
static constexpr int WP_Q2   = 64*256;
static constexpr int WP_TOTAL = WP_CONV + WP_CONVP + WP_PRE1 + WP_PRE2 + 2*WP_EC + WP_Q1 + WP_Q2;

__global__ __launch_bounds__(256) void wprep_kernel(
    const float* __restrict__ conv_w, const float* __restrict__ pre_w1,
    const float* __restrict__ pre_w2, const float* __restrict__ g1_w,
    const float* __restrict__ g2_w,   const float* __restrict__ q_w1,
    const float* __restrict__ q_w2,
    bf16_t* __restrict__ wt_conv, bf16_t* __restrict__ wt_convp,
    bf16_t* __restrict__ wt_pre1,
    bf16_t* __restrict__ wt_pre2, bf16_t* __restrict__ wt_ec1,
    bf16_t* __restrict__ wt_ec2,  bf16_t* __restrict__ wt_q1,
    bf16_t* __restrict__ wt_q2)
{
    int i = blockIdx.x * 256 + threadIdx.x;
    if (i >= WP_TOTAL) return;
    if (i < WP_CONV) { wt_conv[i] = (bf16_t)conv_w[i]; return; }
    i -= WP_CONV;
    if (i < WP_CONVP) {   // [o][pix][c] <- conv_w[(o*256+c)*16 + pix]
        const int o = i >> 12, pix = (i >> 8) & 15, c = i & 255;
        wt_convp[i] = (bf16_t)conv_w[((o * 256 + c) << 4) + pix]; return; }
    i -= WP_CONVP;
    if (i < WP_PRE1) { int n = i / 320, k = i - n * 320;
        wt_pre1[i] = (bf16_t)pre_w1[k * 256 + n]; return; }
    i -= WP_PRE1;
    if (i < WP_PRE2) { int n = i >> 8, k = i & 255;
        wt_pre2[i] = (bf16_t)pre_w2[k * 256 + n]; return; }
    i -= WP_PRE2;
    if (i < WP_EC) { int n = i >> 8, k = i & 255;
        wt_ec1[i] = (bf16_t)(n < 256 ? g1_w[n * 512 + k] : g1_w[(n - 256) * 512 + 256 + k]);
        return; }
    i -= WP_EC;
    if (i < WP_EC) { int n = i >> 8, k = i & 255;
        wt_ec2[i] = (bf16_t)(n < 256 ? g2_w[n * 512 + k] : g2_w[(n - 256) * 512 + 256 + k]);
        return; }
    i -= WP_EC;
    if (i < WP_Q1) { int n = i >> 8, k = i & 255;
        wt_q1[i] = (bf16_t)q_w1[k * 256 + n]; return; }
    i -= WP_Q1;
    { int n = i >> 8, k = i & 255;
        wt_q2[i] = (bf16_t)q_w2[k * 64 + n]; }
}

// ---------------------------------------------------------------------------
// Border zero for padded imgT (verified R2)
// ---------------------------------------------------------------------------
static constexpr int PAD_THREADS = 16 * 2112 * 32;

__global__ __launch_bounds__(256) void pad_border(bf16_t* __restrict__ imgT)
{
    const int idx = blockIdx.x * 256 + threadIdx.x;
    if (idx >= PAD_THREADS) return;
    const int t = idx & 31;
    int pi = idx >> 5;
    const int b = pi / 2112; pi -= b * 2112;
    int y, x;
    if (pi < 544)      { y = pi / 136;              x = pi % 136; }
    else if (pi < 1088){ int j = pi - 544; y = 132 + j / 136; x = j % 136; }
    else { int j = pi - 1088; y = 4 + (j >> 3); int k = j & 7; x = (k < 4) ? k : (128 + k); }
    const uint4 z = {0, 0, 0, 0};
    ((uint4*)(imgT + ((size_t)(b * PY_DIM + y) * PY_DIM + x) * 256))[t] = z;
}

// ---------------------------------------------------------------------------
// Image transpose: img[b][c][y][x] f32 -> imgT[b][y+4][x+4][c] bf16 (verified)
// ---------------------------------------------------------------------------
__global__ __launch_bounds__(256) void transpose_img(
    const float* __restrict__ img, bf16_t* __restrict__ imgT)
{
    __shared__ float T[64][65];
    const int bid = blockIdx.x;
    const int cc = bid & 3;
    const int xh = (bid >> 2) & 1;
    const int y  = (bid >> 3) & 127;
    const int b  = bid >> 10;
    const int t = threadIdx.x;
    const int x0 = xh * 64, c0 = cc * 64;
    {
        const int px = t & 63, cr = t >> 6;
        const float* src = img + ((size_t)(b * 256 + c0 + cr) * 128 + y) * 128 + x0 + px;
        #pragma unroll
        for (int i = 0; i < 16; ++i)
            T[cr + i * 4][px] = src[(size_t)i * 4 * 16384];
    }
    __syncthreads();
    {
        const int cl2 = (t & 31) * 2, pr = t >> 5;
        bf16_t* dst = imgT + ((size_t)(b * PY_DIM + y + 4) * PY_DIM + x0 + 4) * 256 + c0 + cl2;
        #pragma unroll
        for (int i = 0; i < 8; ++i) {
            const int pxl = pr + i * 8;
            bf16x2 w;
            w[0] = (bf16_t)T[cl2][pxl];
            w[1] = (bf16_t)T[cl2 + 1][pxl];
            *(bf16x2*)(dst + (size_t)pxl * 256) = w;
        }
    }
}

// ---------------------------------------------------------------------------
// Conv-gather GEMM v3 (R3-verified): padded channel-last image, 32-row tiles.
// ---------------------------------------------------------------------------
__global__ __launch_bounds__(256) void conv_gather_gemm3(
    const bf16_t* __restrict__ imgT,    // [16][136][136][256], +4 origin
    const bf16_t* __restrict__ Wc,      // [64][16][256]
    const float* __restrict__ conv_b, const float* __restrict__ roi,
    const int* __restrict__ px, const int* __restrict__ py,
    bf16_t* __restrict__ local)
{
    __shared__ bf16_t As[32][136];
    __shared__ bf16_t Bs[64][136];
    const int tid = threadIdx.x, lane = tid & 63, wave = tid >> 6;
    const int wm = wave & 1, wn = wave >> 1;
    const int row0 = blockIdx.x * 32;

    const int ra = tid >> 3, seg = tid & 7;
    const int r = row0 + ra, corner = r & 3, pnt = r >> 2, b = pnt >> 9;
    const int oy = 2 * py[pnt] + (corner & 1) * 4 + 1;
    const int ox = 2 * px[pnt] + ((corner >> 1) & 1) * 4 + 1;
    const bf16_t* imgb = imgT + (size_t)b * IMG_BSTRIDE;
    const int rb = tid >> 2, sq = tid & 3;
    const bf16_t* wrow = Wc + (size_t)rb * 4096 + sq * 8;

    f32x4 acc[2] = {};
    #pragma unroll 1
    for (int s = 0; s < 32; ++s) {
        const int pix = s >> 1, h = s & 1;
        const int iy = oy + (pix >> 2), ix = ox + (pix & 3);
        {
            const bf16_t* srcA = imgb + ((size_t)(iy * PY_DIM + ix)) * 256 + h * 128 + seg * 16;
            *(uint4*)&As[ra][seg * 16]     = *(const uint4*)srcA;
            *(uint4*)&As[ra][seg * 16 + 8] = *(const uint4*)(srcA + 8);
        }
        {
            const bf16_t* srcB = wrow + pix * 256 + h * 128;
            #pragma unroll
            for (int i = 0; i < 4; ++i)
                *(uint4*)&Bs[rb][sq * 8 + i * 32] = *(const uint4*)(srcB + i * 32);
        }
        __syncthreads();
        #pragma unroll
        for (int kk = 0; kk < 128; kk += 32) {
            const int kf = kk + ((lane >> 4) << 3);
            bf16x8 a  = *(const bf16x8*)&As[wm * 16 + (lane & 15)][kf];
            bf16x8 b0 = *(const bf16x8*)&Bs[wn * 32 + (lane & 15)][kf];
            bf16x8 b1 = *(const bf16x8*)&Bs[wn * 32 + 16 + (lane & 15)][kf];
            acc[0] = __builtin_amdgcn_mfma_f32_16x16x32_bf16(a, b0, acc[0], 0, 0, 0);
            acc[1] = __builtin_amdgcn_mfma_f32_16x16x32_bf16(a, b1, acc[1], 0, 0, 0);
        }
        __syncthreads();
    }
    const int crow = (lane >> 4) << 2;
    const int ccol = lane & 15;
    #pragma unroll
    for (int j = 0; j < 2; ++j) {
        const int o = wn * 32 + j * 16 + ccol;
        const float bv = conv_b[o];
        #pragma unroll
        for (int rg = 0; rg < 4; ++rg) {
            const int gr = row0 + wm * 16 + crow + rg;
            const int cn = gr & 3;
            const int pp = gr >> 2;
            const float v = (acc[j][rg] + bv) * roi[pp];
            local[(size_t)pp * 320 + cn * 64 + o] = (bf16_t)v;
        }
    }
}

// ---------------------------------------------------------------------------
// Conv-gather GEMM v1 (fallback for small ws): scattered f32.
// ---------------------------------------------------------------------------
__global__ __launch_bounds__(256) void conv_gather_gemm(
    const float* __restrict__ img, const bf16_t* __restrict__ Wc,
    const float* __restrict__ conv_b, const float* __restrict__ roi,
    const int* __restrict__ px, const int* __restrict__ py,
    bf16_t* __restrict__ local)
{
    __shared__ bf16_t As[64][72];
    __shared__ bf16_t Bs[64][72];
    const int tid = threadIdx.x;
    const int lane = tid & 63;
    const int wave = tid >> 6;
    const int wm = wave & 1, wn = wave >> 1;
    const int row0 = blockIdx.x * 64;
    const int sm = tid >> 2;
    const int cq = tid & 3;
    const int r = row0 + sm;
    const int corner = r & 3;
    const int pnt = r >> 2;
    const int b = pnt >> 9;
    const int oy = 2 * py[pnt] + (corner & 1) * 4;
    const int ox = 2 * px[pnt] + ((corner >> 1) & 1) * 4;
    const int iy0 = oy - 3, ix0 = ox - 3;
    const float* imgb = img + (size_t)b * (256 * 128 * 128);

    f32x4 acc[2][2] = {};
    for (int kt = 0; kt < CONVK; kt += 64) {
        {
            const int c = (kt >> 4) + cq;
            const float* ip = imgb + (size_t)c * (128 * 128);
            alignas(16) bf16_t vals[16];
            #pragma unroll
            for (int ky = 0; ky < 4; ++ky) {
                const int iy = iy0 + ky;
                const bool yok = (unsigned)iy < 128u;
                #pragma unroll
                for (int kx = 0; kx < 4; ++kx) {
                    const int ix = ix0 + kx;
                    float v = (yok && (unsigned)ix < 128u) ? ip[iy * 128 + ix] : 0.0f;
                    vals[ky * 4 + kx] = (bf16_t)v;
                }
            }
            *(uint4*)&As[sm][cq * 16]     = *(const uint4*)&vals[0];
            *(uint4*)&As[sm][cq * 16 + 8] = *(const uint4*)&vals[8];
        }
        {
            const bf16_t* src = Wc + (size_t)sm * CONVK + kt + cq * 16;
            *(uint4*)&Bs[sm][cq * 16]     = *(const uint4*)src;
            *(uint4*)&Bs[sm][cq * 16 + 8] = *(const uint4*)(src + 8);
        }
        __syncthreads();
        #pragma unroll
        for (int kk = 0; kk < 64; kk += 32) {
            const int kf = kk + ((lane >> 4) << 3);
            bf16x8 a0 = *(const bf16x8*)&As[wm * 32 + (lane & 15)][kf];
            bf16x8 a1 = *(const bf16x8*)&As[wm * 32 + 16 + (lane & 15)][kf];
            bf16x8 b0 = *(const bf16x8*)&Bs[wn * 32 + (lane & 15)][kf];
            bf16x8 b1 = *(const bf16x8*)&Bs[wn * 32 + 16 + (lane & 15)][kf];
            acc[0][0] = __builtin_amdgcn_mfma_f32_16x16x32_bf16(a0, b0, acc[0][0], 0, 0, 0);
            acc[0][1] = __builtin_amdgcn_mfma_f32_16x16x32_bf16(a0, b1, acc[0][1], 0, 0, 0);
            acc[1][0] = __builtin_amdgcn_mfma_f32_16x16x32_bf16(a1, b0, acc[1][0], 0, 0, 0);
            acc[1][1] = __builtin_amdgcn_mfma_f32_16x16x32_bf16(a1, b1, acc[1][1], 0, 0, 0);
        }
        __syncthreads();
    }
    const int crow = (lane >> 4) << 2;
    const int ccol = lane & 15;
    #pragma unroll
    for (int i = 0; i < 2; ++i) {
        #pragma unroll
        for (int j = 0; j < 2; ++j) {
            const int o = wn * 32 + j * 16 + ccol;
            const float bv = conv_b[o];
            #pragma unroll
            for (int rg = 0; rg < 4; ++rg) {
                const int gr = row0 + wm * 32 + i * 16 + crow + rg;
                const int cn = gr & 3;
                const int pp = gr >> 2;
                const float v = (acc[i][j][rg] + bv) * roi[pp];
                local[(size_t)pp * 320 + cn * 64 + o] = (bf16_t)v;
            }
        }
    }
}

// ---------------------------------------------------------------------------
// graph_feat fill
// ---------------------------------------------------------------------------
__global__ __launch_bounds__(256) void graph_fill(
    const float* __restrict__ g, bf16_t* __restrict__ local)
{
    const int e = blockIdx.x * 256 + threadIdx.x;
    const int j = e & 63, p = e >> 6;
    const int b = p >> 9, n = p & 511;
    local[(size_t)p * 320 + 256 + j] = (bf16_t)g[((size_t)(b * 64 + j) << 9) + n];
}

// ---------------------------------------------------------------------------
// Generic MFMA GEMM: C[8192][N] = A[8192][K] @ Bt[N][K]^T (+bias, lrelu)
// ---------------------------------------------------------------------------
template<int K, int N, int ACT>
__global__ __launch_bounds__(256) void gemm_bf16(
    const bf16_t* __restrict__ A, const bf16_t* __restrict__ Bt,
    const float* __restrict__ bias, float slope,
    bf16_t* __restrict__ outB, float* __restrict__ outF)
{
    __shared__ bf16_t As[64][72];
    __shared__ bf16_t Bs[64][72];
    const int tid = threadIdx.x;
    const int lane = tid & 63;
    const int wave = tid >> 6;
    const int wm = wave & 1, wn = wave >> 1;
    const int row0 = blockIdx.x * 64;
    const int col0 = blockIdx.y * 64;
    const int sm = tid >> 2;
    const int sq = (tid & 3) << 4;

    f32x4 acc[2][2] = {};
    for (int kt = 0; kt < K; kt += 64) {
        {
            const bf16_t* src = A + (size_t)(row0 + sm) * K + kt + sq;
            *(uint4*)&As[sm][sq]     = *(const uint4*)src;
            *(uint4*)&As[sm][sq + 8] = *(const uint4*)(src + 8);
        }
        {
            const bf16_t* src = Bt + (size_t)(col0 + sm) * K + kt + sq;
            *(uint4*)&Bs[sm][sq]     = *(const uint4*)src;
            *(uint4*)&Bs[sm][sq + 8] = *(const uint4*)(src + 8);
        }
        __syncthreads();
        #pragma unroll
        for (int kk = 0; kk < 64; kk += 32) {
            const int kf = kk + ((lane >> 4) << 3);
            bf16x8 a0 = *(const bf16x8*)&As[wm * 32 + (lane & 15)][kf];
            bf16x8 a1 = *(const bf16x8*)&As[wm * 32 + 16 + (lane & 15)][kf];
            bf16x8 b0 = *(const bf16x8*)&Bs[wn * 32 + (lane & 15)][kf];
            bf16x8 b1 = *(const bf16x8*)&Bs[wn * 32 + 16 + (lane & 15)][kf];
            acc[0][0] = __builtin_amdgcn_mfma_f32_16x16x32_bf16(a0, b0, acc[0][0], 0, 0, 0);
            acc[0][1] = __builtin_amdgcn_mfma_f32_16x16x32_bf16(a0, b1, acc[0][1], 0, 0, 0);
            acc[1][0] = __builtin_amdgcn_mfma_f32_16x16x32_bf16(a1, b0, acc[1][0], 0, 0, 0);
            acc[1][1] = __builtin_amdgcn_mfma_f32_16x16x32_bf16(a1, b1, acc[1][1], 0, 0, 0);
        }
        __syncthreads();
    }
    const int crow = (lane >> 4) << 2;
    const int ccol = lane & 15;
    #pragma unroll
    for (int i = 0; i < 2; ++i) {
        #pragma unroll
        for (int j = 0; j < 2; ++j) {
            const int gcol = col0 + wn * 32 + j * 16 + ccol;
            const float bv = bias ? bias[gcol] : 0.0f;
            #pragma unroll
            for (int rg = 0; rg < 4; ++rg) {
                const int grow = row0 + wm * 32 + i * 16 + crow + rg;
                float v = acc[i][j][rg] + bv;
                if (ACT == 1) v = v >= 0.0f ? v : slope * v;
                if (outB) outB[(size_t)grow * N + gcol] = (bf16_t)v;
                if (outF) outF[(size_t)grow * N + gcol] = v;
            }
        }
    }
}

// ---------------------------------------------------------------------------
// EdgeConv combine (bf16 AB input)
// ---------------------------------------------------------------------------
__global__ __launch_bounds__(256) void edge_combine(
    const bf16_t* __restrict__ AB, const int* __restrict__ knn,
    const float* __restrict__ gamma, const float* __restrict__ beta,
    const float* __restrict__ mean,  const float* __restrict__ var,
    bf16_t* __restrict__ outB, float* __restrict__ outT)
{
    const int p = blockIdx.x;
    const int b = p >> 9, n = p & 511;
    const int o = threadIdx.x;
    const float sc = gamma[o] / sqrtf(var[o] + 1e-5f);
    const float sh = beta[o] - mean[o] * sc;
    const bf16_t* rowp = AB + (size_t)p * 512;
    const float d = (float)rowp[256 + o] - (float)rowp[o];
    const bf16_t* batch = AB + ((size_t)(b << 9)) * 512;
    float m = -3.4e38f;
    #pragma unroll 4
    for (int k = 0; k < 20; ++k) {
        const int q = knn[n * 20 + k];
        const float v = (float)batch[(size_t)q * 512 + o] + d;
        float y = v * sc + sh;
        y = y >= 0.0f ? y : 0.2f * y;
        m = fmaxf(m, y);
    }
    outB[(size_t)p * 256 + o] = (bf16_t)m;
    if (outT) outT[((size_t)(b * 256 + o) << 9) + n] = m;
}

// ---------------------------------------------------------------------------
// Head final layer
// ---------------------------------------------------------------------------
__global__ __launch_bounds__(256) void q3_kernel(
    const bf16_t* __restrict__ Z, const float* __restrict__ w3,
    const float* __restrict__ b3, float* __restrict__ out)
{
    const int p = blockIdx.x * 256 + threadIdx.x;
    const int b = p >> 9, n = p & 511;
    const bf16_t* q = Z + (size_t)p * 64;
    float s0 = b3[0], s1 = b3[1];
    #pragma unroll
    for (int c = 0; c < 64; ++c) {
        const float v = (float)q[c];
        s0 += v * w3[2 * c];
        s1 += v * w3[2 * c + 1];
    }
    out[(size_t)(b * 2 + 0) * 512 + n] = s0;
    out[(size_t)(b * 2 + 1) * 512 + n] = s1;
}

// ---------------------------------------------------------------------------
extern "C" void kernel_launch(void* const* d_in, const int* in_sizes, int n_in,
                              void* d_out, int out_size, void* d_ws, size_t ws_size,
                              hipStream_t stream)
{
    const float* img      = (const float*)d_in[0];
    const float* graph    = (const float*)d_in[1];
    const float* roi      = (const float*)d_in[2];
    const int*   px       = (const int*)d_in[3];
    const int*   py       = (const int*)d_in[4];
    const int*   knn      = (const int*)d_in[5];
    const float* conv_w   = (const float*)d_in[6];
    const float* conv_b   = (const float*)d_in[7];
    const float* pre_w1   = (const float*)d_in[8];
    const float* pre_b1   = (const float*)d_in[9];
    const float* pre_w2   = (const float*)d_in[10];
    const float* pre_b2   = (const float*)d_in[11];
    const float* g1_w     = (const float*)d_in[12];
    const float* g1_gamma = (const float*)d_in[13];
    const float* g1_beta  = (const float*)d_in[14];
    const float* g1_mean  = (const float*)d_in[15];
    const float* g1_var   = (const float*)d_in[16];
    const float* g2_w     = (const float*)d_in[17];
    const float* g2_gamma = (const float*)d_in[18];
    const float* g2_beta  = (const float*)d_in[19];
    const float* g2_mean  = (const float*)d_in[20];
    const float* g2_var   = (const float*)d_in[21];
    const float* q_w1     = (const float*)d_in[22];
    const float* q_b1     = (const float*)d_in[23];
    const float* q_w2     = (const float*)d_in[24];
    const float* q_b2     = (const float*)d_in[25];
    const float* q_w3     = (const float*)d_in[26];
    const float* q_b3     = (const float*)d_in[27];
    float* out = (float*)d_out;

    if (ws_size < WS_BASE) return;

    char* ws = (char*)d_ws;
    bf16_t* wt_conv  = (bf16_t*)(ws + OFF_WCONV_OLD);
    bf16_t* wt_convp = (bf16_t*)(ws + OFF_WCONVP);
    bf16_t* wt_pre1  = (bf16_t*)(ws + OFF_WPRE1);
    bf16_t* wt_pre2  = (bf16_t*)(ws + OFF_WPRE2);
    bf16_t* wt_ec1   = (bf16_t*)(ws + OFF_WEC1);
    bf16_t* wt_ec2   = (bf16_t*)(ws + OFF_WEC2);
    bf16_t* wt_q1    = (bf16_t*)(ws + OFF_WQ1);
    bf16_t* wt_q2    = (bf16_t*)(ws + OFF_WQ2);
    bf16_t* local    = (bf16_t*)(ws + OFF_LOCAL);
    bf16_t* X        = (bf16_t*)(ws + OFF_X);
    bf16_t* Y        = (bf16_t*)(ws + OFF_Y);
    bf16_t* Z        = (bf16_t*)(ws + OFF_Z);
    bf16_t* AB       = (bf16_t*)(ws + OFF_UNION);
    bf16_t* imgT     = (bf16_t*)(ws + OFF_UNION);

    const bool big = ws_size >= WS_FULL;

    wprep_kernel<<<(WP_TOTAL + 255) / 256, 256, 0, stream>>>(
        conv_w, pre_w1, pre_w2, g1_w, g2_w, q_w1, q_w2,
        wt_conv, wt_convp, wt_pre1, wt_pre2, wt_ec1, wt_ec2, wt_q1, wt_q2);

    if (big) {
        pad_border<<<(PAD_THREADS + 255) / 256, 256, 0, stream>>>(imgT);
        transpose_img<<<16 * 128 * 2 * 4, 256, 0, stream>>>(img, imgT);
        conv_gather_gemm3<<<CONVM / 32, 256, 0, stream>>>(
            imgT, wt_convp, conv_b, roi, px, py, local);
    } else {
        conv_gather_gemm<<<CONVM / 64, 256, 0, stream>>>(
            img, wt_conv, conv_b, roi, px, py, local);
    }

    graph_fill<<<(PTS * 64) / 256, 256, 0, stream>>>(graph, local);

    gemm_bf16<320, 256, 1><<<dim3(PTS / 64, 4), 256, 0, stream>>>(
        local, wt_pre1, pre_b1, 0.01f, X, nullptr);
    gemm_bf16<256, 256, 1><<<dim3(PTS / 64, 4), 256, 0, stream>>>(
        X, wt_pre2, pre_b2, 0.01f, Y, nullptr);

    gemm_bf16<256, 512, 0><<<dim3(PTS / 64, 8), 256, 0, stream>>>(
        Y, wt_ec1, nullptr, 0.0f, AB, nullptr);
    edge_combine<<<PTS, 256, 0, stream>>>(
        AB, knn, g1_gamma, g1_beta, g1_mean, g1_var, X, nullptr);

    gemm_bf16<256, 512, 0><<<dim3(PTS / 64, 8), 256, 0, stream>>>(
        X, wt_ec2, nullptr, 0.0f, AB, nullptr);
    edge_combine<<<PTS, 256, 0, stream>>>(
        AB, knn, g2_gamma, g2_beta, g2_mean, g2_var, Y, out + 16384);

    gemm_bf16<256, 256, 1><<<dim3(PTS / 64, 4), 256, 0, stream>>>(
        Y, wt_q1, q_b1, 0.01f, X, nullptr);
    gemm_bf16<256, 64, 1><<<dim3(PTS / 64, 1), 256, 0, stream>>>(
        X, wt_q2, q_b2, 0.01f, Z, nullptr);
    q3_kernel<<<PTS / 256, 256, 0, stream>>>(Z, q_w3, q_b3, out);
}

// Round 10
// 261.706 us; speedup vs baseline: 1.2817x; 1.0086x over previous
//
#include <hip/hip_runtime.h>

// ---------------------------------------------------------------------------
// Refine_moduleGNN: pad+transpose -> gather conv (pipelined v3) -> pre-MLP ->
// 2x EdgeConv -> head. MFMA bf16.
// R9 = 263.9us best (R3 structure + bf16 AB).
// R10: conv_gather_gemm3p -- T14 async-STAGE software pipeline (register
//      prefetch of step s+1 during MFMA of step s). Only change vs R9.
// ---------------------------------------------------------------------------

typedef __bf16 bf16_t;
typedef bf16_t bf16x2 __attribute__((ext_vector_type(2)));
typedef bf16_t bf16x8 __attribute__((ext_vector_type(8)));
typedef float  f32x4  __attribute__((ext_vector_type(4)));

static constexpr int BATCH = 16;
static constexpr int NPT   = 512;
static constexpr int PTS   = BATCH * NPT;   // 8192
static constexpr int CONVM = PTS * 4;       // 32768 conv rows
static constexpr int CONVK = 4096;          // 256*4*4

// padded image dims (+4 origin)
static constexpr int PY_DIM = 136;
static constexpr size_t IMG_BSTRIDE = (size_t)PY_DIM * PY_DIM * 256;

// ---- workspace layout (bytes) ----
static constexpr size_t OFF_WCONV_OLD = 0;                                // [64][4096] (c,pix)
static constexpr size_t OFF_WCONVP    = OFF_WCONV_OLD + (size_t)64*4096*2;// [64][16][256]
static constexpr size_t OFF_WPRE1     = OFF_WCONVP    + (size_t)64*4096*2;
static constexpr size_t OFF_WPRE2     = OFF_WPRE1     + (size_t)256*320*2;
static constexpr size_t OFF_WEC1      = OFF_WPRE2     + (size_t)256*256*2;
static constexpr size_t OFF_WEC2      = OFF_WEC1      + (size_t)512*256*2;
static constexpr size_t OFF_WQ1       = OFF_WEC2      + (size_t)512*256*2;
static constexpr size_t OFF_WQ2       = OFF_WQ1       + (size_t)256*256*2;
static constexpr size_t OFF_LOCAL     = OFF_WQ2       + (size_t)64*256*2; // [8192][320] bf16
static constexpr size_t OFF_X         = OFF_LOCAL + (size_t)PTS*320*2;
static constexpr size_t OFF_Y         = OFF_X     + (size_t)PTS*256*2;
static constexpr size_t OFF_Z         = OFF_Y     + (size_t)PTS*256*2;    // [8192][64]
// union region: AB bf16 [8192][512] (edgeconv) | imgT (conv phase only)
static constexpr size_t OFF_UNION     = OFF_Z     + (size_t)PTS*64*2;
static constexpr size_t AB_BYTES      = (size_t)PTS*512*2;                 // 8 MB
static constexpr size_t IMGT_BYTES    = (size_t)16*IMG_BSTRIDE*2;          // ~145 MB
static constexpr size_t WS_BASE       = OFF_UNION + AB_BYTES;
static constexpr size_t WS_FULL       = OFF_UNION + IMGT_BYTES;

// ---------------------------------------------------------------------------
// Weight prep
// ---------------------------------------------------------------------------
static constexpr int WP_CONV  = 64*4096;
static constexpr int WP_CONVP = 64*4096;
static constexpr int WP_PRE1 = 256*320;
static constexpr int WP_PRE2 = 256*256;
static constexpr int WP_EC   = 512*256;
static constexpr int WP_Q1   = 256*256;
static constexpr int WP_Q2   = 64*256;
static constexpr int WP_TOTAL = WP_CONV + WP_CONVP + WP_PRE1 + WP_PRE2 + 2*WP_EC + WP_Q1 + WP_Q2;

__global__ __launch_bounds__(256) void wprep_kernel(
    const float* __restrict__ conv_w, const float* __restrict__ pre_w1,
    const float* __restrict__ pre_w2, const float* __restrict__ g1_w,
    const float* __restrict__ g2_w,   const float* __restrict__ q_w1,
    const float* __restrict__ q_w2,
    bf16_t* __restrict__ wt_conv, bf16_t* __restrict__ wt_convp,
    bf16_t* __restrict__ wt_pre1,
    bf16_t* __restrict__ wt_pre2, bf16_t* __restrict__ wt_ec1,
    bf16_t* __restrict__ wt_ec2,  bf16_t* __restrict__ wt_q1,
    bf16_t* __restrict__ wt_q2)
{
    int i = blockIdx.x * 256 + threadIdx.x;
    if (i >= WP_TOTAL) return;
    if (i < WP_CONV) { wt_conv[i] = (bf16_t)conv_w[i]; return; }
    i -= WP_CONV;
    if (i < WP_CONVP) {   // [o][pix][c] <- conv_w[(o*256+c)*16 + pix]
        const int o = i >> 12, pix = (i >> 8) & 15, c = i & 255;
        wt_convp[i] = (bf16_t)conv_w[((o * 256 + c) << 4) + pix]; return; }
    i -= WP_CONVP;
    if (i < WP_PRE1) { int n = i / 320, k = i - n * 320;
        wt_pre1[i] = (bf16_t)pre_w1[k * 256 + n]; return; }
    i -= WP_PRE1;
    if (i < WP_PRE2) { int n = i >> 8, k = i & 255;
        wt_pre2[i] = (bf16_t)pre_w2[k * 256 + n]; return; }
    i -= WP_PRE2;
    if (i < WP_EC) { int n = i >> 8, k = i & 255;
        wt_ec1[i] = (bf16_t)(n < 256 ? g1_w[n * 512 + k] : g1_w[(n - 256) * 512 + 256 + k]);
        return; }
    i -= WP_EC;
    if (i < WP_EC) { int n = i >> 8, k = i & 255;
        wt_ec2[i] = (bf16_t)(n < 256 ? g2_w[n * 512 + k] : g2_w[(n - 256) * 512 + 256 + k]);
        return; }
    i -= WP_EC;
    if (i < WP_Q1) { int n = i >> 8, k = i & 255;
        wt_q1[i] = (bf16_t)q_w1[k * 256 + n]; return; }
    i -= WP_Q1;
    { int n = i >> 8, k = i & 255;
        wt_q2[i] = (bf16_t)q_w2[k * 64 + n]; }
}

// ---------------------------------------------------------------------------
// Border zero for padded imgT (verified R2)
// ---------------------------------------------------------------------------
static constexpr int PAD_THREADS = 16 * 2112 * 32;

__global__ __launch_bounds__(256) void pad_border(bf16_t* __restrict__ imgT)
{
    const int idx = blockIdx.x * 256 + threadIdx.x;
    if (idx >= PAD_THREADS) return;
    const int t = idx & 31;
    int pi = idx >> 5;
    const int b = pi / 2112; pi -= b * 2112;
    int y, x;
    if (pi < 544)      { y = pi / 136;              x = pi % 136; }
    else if (pi < 1088){ int j = pi - 544; y = 132 + j / 136; x = j % 136; }
    else { int j = pi - 1088; y = 4 + (j >> 3); int k = j & 7; x = (k < 4) ? k : (128 + k); }
    const uint4 z = {0, 0, 0, 0};
    ((uint4*)(imgT + ((size_t)(b * PY_DIM + y) * PY_DIM + x) * 256))[t] = z;
}

// ---------------------------------------------------------------------------
// Image transpose: img[b][c][y][x] f32 -> imgT[b][y+4][x+4][c] bf16 (verified)
// ---------------------------------------------------------------------------
__global__ __launch_bounds__(256) void transpose_img(
    const float* __restrict__ img, bf16_t* __restrict__ imgT)
{
    __shared__ float T[64][65];
    const int bid = blockIdx.x;
    const int cc = bid & 3;
    const int xh = (bid >> 2) & 1;
    const int y  = (bid >> 3) & 127;
    const int b  = bid >> 10;
    const int t = threadIdx.x;
    const int x0 = xh * 64, c0 = cc * 64;
    {
        const int px = t & 63, cr = t >> 6;
        const float* src = img + ((size_t)(b * 256 + c0 + cr) * 128 + y) * 128 + x0 + px;
        #pragma unroll
        for (int i = 0; i < 16; ++i)
            T[cr + i * 4][px] = src[(size_t)i * 4 * 16384];
    }
    __syncthreads();
    {
        const int cl2 = (t & 31) * 2, pr = t >> 5;
        bf16_t* dst = imgT + ((size_t)(b * PY_DIM + y + 4) * PY_DIM + x0 + 4) * 256 + c0 + cl2;
        #pragma unroll
        for (int i = 0; i < 8; ++i) {
            const int pxl = pr + i * 8;
            bf16x2 w;
            w[0] = (bf16_t)T[cl2][pxl];
            w[1] = (bf16_t)T[cl2 + 1][pxl];
            *(bf16x2*)(dst + (size_t)pxl * 256) = w;
        }
    }
}

// ---------------------------------------------------------------------------
// Conv-gather GEMM v3p: R3-verified v3 body + T14 register-prefetch pipeline.
// Loads for K-step s+1 issue right after step s's ds_writes; their wait
// lands at step s+1's ds_write, hiding ~1 step of L3 latency.
// ---------------------------------------------------------------------------
__global__ __launch_bounds__(256) void conv_gather_gemm3p(
    const bf16_t* __restrict__ imgT,    // [16][136][136][256], +4 origin
    const bf16_t* __restrict__ Wc,      // [64][16][256]
    const float* __restrict__ conv_b, const float* __restrict__ roi,
    const int* __restrict__ px, const int* __restrict__ py,
    bf16_t* __restrict__ local)
{
    __shared__ bf16_t As[32][136];
    __shared__ bf16_t Bs[64][136];
    const int tid = threadIdx.x, lane = tid & 63, wave = tid >> 6;
    const int wm = wave & 1, wn = wave >> 1;
    const int row0 = blockIdx.x * 32;

    const int ra = tid >> 3, seg = tid & 7;
    const int r = row0 + ra, corner = r & 3, pnt = r >> 2, b = pnt >> 9;
    const int oy = 2 * py[pnt] + (corner & 1) * 4 + 1;
    const int ox = 2 * px[pnt] + ((corner >> 1) & 1) * 4 + 1;
    const bf16_t* imgb = imgT + (size_t)b * IMG_BSTRIDE;
    const int rb = tid >> 2, sq = tid & 3;
    const bf16_t* wrow = Wc + (size_t)rb * 4096 + sq * 8;

    uint4 a0, a1, b0, b1, b2, b3;
    // prefetch step 0
    {
        const bf16_t* srcA = imgb + ((size_t)((oy) * PY_DIM + ox)) * 256 + seg * 16;
        a0 = *(const uint4*)srcA;
        a1 = *(const uint4*)(srcA + 8);
        const bf16_t* srcB = wrow;
        b0 = *(const uint4*)srcB;
        b1 = *(const uint4*)(srcB + 32);
        b2 = *(const uint4*)(srcB + 64);
        b3 = *(const uint4*)(srcB + 96);
    }

    f32x4 acc[2] = {};
    #pragma unroll 1
    for (int s = 0; s < 32; ++s) {
        __syncthreads();   // prev MFMA reads done; LDS writable
        *(uint4*)&As[ra][seg * 16]     = a0;
        *(uint4*)&As[ra][seg * 16 + 8] = a1;
        *(uint4*)&Bs[rb][sq * 8]       = b0;
        *(uint4*)&Bs[rb][sq * 8 + 32]  = b1;
        *(uint4*)&Bs[rb][sq * 8 + 64]  = b2;
        *(uint4*)&Bs[rb][sq * 8 + 96]  = b3;
        if (s < 31) {
            const int sn = s + 1;
            const int pix = sn >> 1, h = sn & 1;
            const int iy = oy + (pix >> 2), ix = ox + (pix & 3);
            const bf16_t* srcA = imgb + ((size_t)(iy * PY_DIM + ix)) * 256 + h * 128 + seg * 16;
            a0 = *(const uint4*)srcA;
            a1 = *(const uint4*)(srcA + 8);
            const bf16_t* srcB = wrow + pix * 256 + h * 128;
            b0 = *(const uint4*)srcB;
            b1 = *(const uint4*)(srcB + 32);
            b2 = *(const uint4*)(srcB + 64);
            b3 = *(const uint4*)(srcB + 96);
        }
        __syncthreads();   // LDS visible to all
        #pragma unroll
        for (int kk = 0; kk < 128; kk += 32) {
            const int kf = kk + ((lane >> 4) << 3);
            bf16x8 a  = *(const bf16x8*)&As[wm * 16 + (lane & 15)][kf];
            bf16x8 bb0 = *(const bf16x8*)&Bs[wn * 32 + (lane & 15)][kf];
            bf16x8 bb1 = *(const bf16x8*)&Bs[wn * 32 + 16 + (lane & 15)][kf];
            acc[0] = __builtin_amdgcn_mfma_f32_16x16x32_bf16(a, bb0, acc[0], 0, 0, 0);
            acc[1] = __builtin_amdgcn_mfma_f32_16x16x32_bf16(a, bb1, acc[1], 0, 0, 0);
        }
    }
    const int crow = (lane >> 4) << 2;
    const int ccol = lane & 15;
    #pragma unroll
    for (int j = 0; j < 2; ++j) {
        const int o = wn * 32 + j * 16 + ccol;
        const float bv = conv_b[o];
        #pragma unroll
        for (int rg = 0; rg < 4; ++rg) {
            const int gr = row0 + wm * 16 + crow + rg;
            const int cn = gr & 3;
            const int pp = gr >> 2;
            const float v = (acc[j][rg] + bv) * roi[pp];
            local[(size_t)pp * 320 + cn * 64 + o] = (bf16_t)v;
        }
    }
}

// ---------------------------------------------------------------------------
// Conv-gather GEMM v1 (fallback for small ws): scattered f32.
// ---------------------------------------------------------------------------
__global__ __launch_bounds__(256) void conv_gather_gemm(
    const float* __restrict__ img, const bf16_t* __restrict__ Wc,
    const float* __restrict__ conv_b, const float* __restrict__ roi,
    const int* __restrict__ px, const int* __restrict__ py,
    bf16_t* __restrict__ local)
{
    __shared__ bf16_t As[64][72];
    __shared__ bf16_t Bs[64][72];
    const int tid = threadIdx.x;
    const int lane = tid & 63;
    const int wave = tid >> 6;
    const int wm = wave & 1, wn = wave >> 1;
    const int row0 = blockIdx.x * 64;
    const int sm = tid >> 2;
    const int cq = tid & 3;
    const int r = row0 + sm;
    const int corner = r & 3;
    const int pnt = r >> 2;
    const int b = pnt >> 9;
    const int oy = 2 * py[pnt] + (corner & 1) * 4;
    const int ox = 2 * px[pnt] + ((corner >> 1) & 1) * 4;
    const int iy0 = oy - 3, ix0 = ox - 3;
    const float* imgb = img + (size_t)b * (256 * 128 * 128);

    f32x4 acc[2][2] = {};
    for (int kt = 0; kt < CONVK; kt += 64) {
        {
            const int c = (kt >> 4) + cq;
            const float* ip = imgb + (size_t)c * (128 * 128);
            alignas(16) bf16_t vals[16];
            #pragma unroll
            for (int ky = 0; ky < 4; ++ky) {
                const int iy = iy0 + ky;
                const bool yok = (unsigned)iy < 128u;
                #pragma unroll
                for (int kx = 0; kx < 4; ++kx) {
                    const int ix = ix0 + kx;
                    float v = (yok && (unsigned)ix < 128u) ? ip[iy * 128 + ix] : 0.0f;
                    vals[ky * 4 + kx] = (bf16_t)v;
                }
            }
            *(uint4*)&As[sm][cq * 16]     = *(const uint4*)&vals[0];
            *(uint4*)&As[sm][cq * 16 + 8] = *(const uint4*)&vals[8];
        }
        {
            const bf16_t* src = Wc + (size_t)sm * CONVK + kt + cq * 16;
            *(uint4*)&Bs[sm][cq * 16]     = *(const uint4*)src;
            *(uint4*)&Bs[sm][cq * 16 + 8] = *(const uint4*)(src + 8);
        }
        __syncthreads();
        #pragma unroll
        for (int kk = 0; kk < 64; kk += 32) {
            const int kf = kk + ((lane >> 4) << 3);
            bf16x8 a0 = *(const bf16x8*)&As[wm * 32 + (lane & 15)][kf];
            bf16x8 a1 = *(const bf16x8*)&As[wm * 32 + 16 + (lane & 15)][kf];
            bf16x8 b0 = *(const bf16x8*)&Bs[wn * 32 + (lane & 15)][kf];
            bf16x8 b1 = *(const bf16x8*)&Bs[wn * 32 + 16 + (lane & 15)][kf];
            acc[0][0] = __builtin_amdgcn_mfma_f32_16x16x32_bf16(a0, b0, acc[0][0], 0, 0, 0);
            acc[0][1] = __builtin_amdgcn_mfma_f32_16x16x32_bf16(a0, b1, acc[0][1], 0, 0, 0);
            acc[1][0] = __builtin_amdgcn_mfma_f32_16x16x32_bf16(a1, b0, acc[1][0], 0, 0, 0);
            acc[1][1] = __builtin_amdgcn_mfma_f32_16x16x32_bf16(a1, b1, acc[1][1], 0, 0, 0);
        }
        __syncthreads();
    }
    const int crow = (lane >> 4) << 2;
    const int ccol = lane & 15;
    #pragma unroll
    for (int i = 0; i < 2; ++i) {
        #pragma unroll
        for (int j = 0; j < 2; ++j) {
            const int o = wn * 32 + j * 16 + ccol;
            const float bv = conv_b[o];
            #pragma unroll
            for (int rg = 0; rg < 4; ++rg) {
                const int gr = row0 + wm * 32 + i * 16 + crow + rg;
                const int cn = gr & 3;
                const int pp = gr >> 2;
                const float v = (acc[i][j][rg] + bv) * roi[pp];
                local[(size_t)pp * 320 + cn * 64 + o] = (bf16_t)v;
            }
        }
    }
}

// ---------------------------------------------------------------------------
// graph_feat fill
// ---------------------------------------------------------------------------
__global__ __launch_bounds__(256) void graph_fill(
    const float* __restrict__ g, bf16_t* __restrict__ local)
{
    const int e = blockIdx.x * 256 + threadIdx.x;
    const int j = e & 63, p = e >> 6;
    const int b = p >> 9, n = p & 511;
    local[(size_t)p * 320 + 256 + j] = (bf16_t)g[((size_t)(b * 64 + j) << 9) + n];
}

// ---------------------------------------------------------------------------
// Generic MFMA GEMM: C[8192][N] = A[8192][K] @ Bt[N][K]^T (+bias, lrelu)
// ---------------------------------------------------------------------------
template<int K, int N, int ACT>
__global__ __launch_bounds__(256) void gemm_bf16(
    const bf16_t* __restrict__ A, const bf16_t* __restrict__ Bt,
    const float* __restrict__ bias, float slope,
    bf16_t* __restrict__ outB, float* __restrict__ outF)
{
    __shared__ bf16_t As[64][72];
    __shared__ bf16_t Bs[64][72];
    const int tid = threadIdx.x;
    const int lane = tid & 63;
    const int wave = tid >> 6;
    const int wm = wave & 1, wn = wave >> 1;
    const int row0 = blockIdx.x * 64;
    const int col0 = blockIdx.y * 64;
    const int sm = tid >> 2;
    const int sq = (tid & 3) << 4;

    f32x4 acc[2][2] = {};
    for (int kt = 0; kt < K; kt += 64) {
        {
            const bf16_t* src = A + (size_t)(row0 + sm) * K + kt + sq;
            *(uint4*)&As[sm][sq]     = *(const uint4*)src;
            *(uint4*)&As[sm][sq + 8] = *(const uint4*)(src + 8);
        }
        {
            const bf16_t* src = Bt + (size_t)(col0 + sm) * K + kt + sq;
            *(uint4*)&Bs[sm][sq]     = *(const uint4*)src;
            *(uint4*)&Bs[sm][sq + 8] = *(const uint4*)(src + 8);
        }
        __syncthreads();
        #pragma unroll
        for (int kk = 0; kk < 64; kk += 32) {
            const int kf = kk + ((lane >> 4) << 3);
            bf16x8 a0 = *(const bf16x8*)&As[wm * 32 + (lane & 15)][kf];
            bf16x8 a1 = *(const bf16x8*)&As[wm * 32 + 16 + (lane & 15)][kf];
            bf16x8 b0 = *(const bf16x8*)&Bs[wn * 32 + (lane & 15)][kf];
            bf16x8 b1 = *(const bf16x8*)&Bs[wn * 32 + 16 + (lane & 15)][kf];
            acc[0][0] = __builtin_amdgcn_mfma_f32_16x16x32_bf16(a0, b0, acc[0][0], 0, 0, 0);
            acc[0][1] = __builtin_amdgcn_mfma_f32_16x16x32_bf16(a0, b1, acc[0][1], 0, 0, 0);
            acc[1][0] = __builtin_amdgcn_mfma_f32_16x16x32_bf16(a1, b0, acc[1][0], 0, 0, 0);
            acc[1][1] = __builtin_amdgcn_mfma_f32_16x16x32_bf16(a1, b1, acc[1][1], 0, 0, 0);
        }
        __syncthreads();
    }
    const int crow = (lane >> 4) << 2;
    const int ccol = lane & 15;
    #pragma unroll
    for (int i = 0; i < 2; ++i) {
        #pragma unroll
        for (int j = 0; j < 2; ++j) {
            const int gcol = col0 + wn * 32 + j * 16 + ccol;
            const float bv = bias ? bias[gcol] : 0.0f;
            #pragma unroll
            for (int rg = 0; rg < 4; ++rg) {
                const int grow = row0 + wm * 32 + i * 16 + crow + rg;
                float v = acc[i][j][rg] + bv;
                if (ACT == 1) v = v >= 0.0f ? v : slope * v;
                if (outB) outB[(size_t)grow * N + gcol] = (bf16_t)v;
                if (outF) outF[(size_t)grow * N + gcol] = v;
            }
        }
    }
}

// ---------------------------------------------------------------------------
// EdgeConv combine (bf16 AB input)
// ---------------------------------------------------------------------------
__global__ __launch_bounds__(256) void edge_combine(
    const bf16_t* __restrict__ AB, const int* __restrict__ knn,
    const float* __restrict__ gamma, const float* __restrict__ beta,
    const float* __restrict__ mean,  const float* __restrict__ var,
    bf16_t* __restrict__ outB, float* __restrict__ outT)
{
    const int p = blockIdx.x;
    const int b = p >> 9, n = p & 511;
    const int o = threadIdx.x;
    const float sc = gamma[o] / sqrtf(var[o] + 1e-5f);
    const float sh = beta[o] - mean[o] * sc;
    const bf16_t* rowp = AB + (size_t)p * 512;
    const float d = (float)rowp[256 + o] - (float)rowp[o];
    const bf16_t* batch = AB + ((size_t)(b << 9)) * 512;
    float m = -3.4e38f;
    #pragma unroll 4
    for (int k = 0; k < 20; ++k) {
        const int q = knn[n * 20 + k];
        const float v = (float)batch[(size_t)q * 512 + o] + d;
        float y = v * sc + sh;
        y = y >= 0.0f ? y : 0.2f * y;
        m = fmaxf(m, y);
    }
    outB[(size_t)p * 256 + o] = (bf16_t)m;
    if (outT) outT[((size_t)(b * 256 + o) << 9) + n] = m;
}

// ---------------------------------------------------------------------------
// Head final layer
// ---------------------------------------------------------------------------
__global__ __launch_bounds__(256) void q3_kernel(
    const bf16_t* __restrict__ Z, const float* __restrict__ w3,
    const float* __restrict__ b3, float* __restrict__ out)
{
    const int p = blockIdx.x * 256 + threadIdx.x;
    const int b = p >> 9, n = p & 511;
    const bf16_t* q = Z + (size_t)p * 64;
    float s0 = b3[0], s1 = b3[1];
    #pragma unroll
    for (int c = 0; c < 64; ++c) {
        const float v = (float)q[c];
        s0 += v * w3[2 * c];
        s1 += v * w3[2 * c + 1];
    }
    out[(size_t)(b * 2 + 0) * 512 + n] = s0;
    out[(size_t)(b * 2 + 1) * 512 + n] = s1;
}

// ---------------------------------------------------------------------------
extern "C" void kernel_launch(void* const* d_in, const int* in_sizes, int n_in,
                              void* d_out, int out_size, void* d_ws, size_t ws_size,
                              hipStream_t stream)
{
    const float* img      = (const float*)d_in[0];
    const float* graph    = (const float*)d_in[1];
    const float* roi      = (const float*)d_in[2];
    const int*   px       = (const int*)d_in[3];
    const int*   py       = (const int*)d_in[4];
    const int*   knn      = (const int*)d_in[5];
    const float* conv_w   = (const float*)d_in[6];
    const float* conv_b   = (const float*)d_in[7];
    const float* pre_w1   = (const float*)d_in[8];
    const float* pre_b1   = (const float*)d_in[9];
    const float* pre_w2   = (const float*)d_in[10];
    const float* pre_b2   = (const float*)d_in[11];
    const float* g1_w     = (const float*)d_in[12];
    const float* g1_gamma = (const float*)d_in[13];
    const float* g1_beta  = (const float*)d_in[14];
    const float* g1_mean  = (const float*)d_in[15];
    const float* g1_var   = (const float*)d_in[16];
    const float* g2_w     = (const float*)d_in[17];
    const float* g2_gamma = (const float*)d_in[18];
    const float* g2_beta  = (const float*)d_in[19];
    const float* g2_mean  = (const float*)d_in[20];
    const float* g2_var   = (const float*)d_in[21];
    const float* q_w1     = (const float*)d_in[22];
    const float* q_b1     = (const float*)d_in[23];
    const float* q_w2     = (const float*)d_in[24];
    const float* q_b2     = (const float*)d_in[25];
    const float* q_w3     = (const float*)d_in[26];
    const float* q_b3     = (const float*)d_in[27];
    float* out = (float*)d_out;

    if (ws_size < WS_BASE) return;

    char* ws = (char*)d_ws;
    bf16_t* wt_conv  = (bf16_t*)(ws + OFF_WCONV_OLD);
    bf16_t* wt_convp = (bf16_t*)(ws + OFF_WCONVP);
    bf16_t* wt_pre1  = (bf16_t*)(ws + OFF_WPRE1);
    bf16_t* wt_pre2  = (bf16_t*)(ws + OFF_WPRE2);
    bf16_t* wt_ec1   = (bf16_t*)(ws + OFF_WEC1);
    bf16_t* wt_ec2   = (bf16_t*)(ws + OFF_WEC2);
    bf16_t* wt_q1    = (bf16_t*)(ws + OFF_WQ1);
    bf16_t* wt_q2    = (bf16_t*)(ws + OFF_WQ2);
    bf16_t* local    = (bf16_t*)(ws + OFF_LOCAL);
    bf16_t* X        = (bf16_t*)(ws + OFF_X);
    bf16_t* Y        = (bf16_t*)(ws + OFF_Y);
    bf16_t* Z        = (bf16_t*)(ws + OFF_Z);
    bf16_t* AB       = (bf16_t*)(ws + OFF_UNION);
    bf16_t* imgT     = (bf16_t*)(ws + OFF_UNION);

    const bool big = ws_size >= WS_FULL;

    wprep_kernel<<<(WP_TOTAL + 255) / 256, 256, 0, stream>>>(
        conv_w, pre_w1, pre_w2, g1_w, g2_w, q_w1, q_w2,
        wt_conv, wt_convp, wt_pre1, wt_pre2, wt_ec1, wt_ec2, wt_q1, wt_q2);

    if (big) {
        pad_border<<<(PAD_THREADS + 255) / 256, 256, 0, stream>>>(imgT);
        transpose_img<<<16 * 128 * 2 * 4, 256, 0, stream>>>(img, imgT);
        conv_gather_gemm3p<<<CONVM / 32, 256, 0, stream>>>(
            imgT, wt_convp, conv_b, roi, px, py, local);
    } else {
        conv_gather_gemm<<<CONVM / 64, 256, 0, stream>>>(
            img, wt_conv, conv_b, roi, px, py, local);
    }

    graph_fill<<<(PTS * 64) / 256, 256, 0, stream>>>(graph, local);

    gemm_bf16<320, 256, 1><<<dim3(PTS / 64, 4), 256, 0, stream>>>(
        local, wt_pre1, pre_b1, 0.01f, X, nullptr);
    gemm_bf16<256, 256, 1><<<dim3(PTS / 64, 4), 256, 0, stream>>>(
        X, wt_pre2, pre_b2, 0.01f, Y, nullptr);

    gemm_bf16<256, 512, 0><<<dim3(PTS / 64, 8), 256, 0, stream>>>(
        Y, wt_ec1, nullptr, 0.0f, AB, nullptr);
    edge_combine<<<PTS, 256, 0, stream>>>(
        AB, knn, g1_gamma, g1_beta, g1_mean, g1_var, X, nullptr);

    gemm_bf16<256, 512, 0><<<dim3(PTS / 64, 8), 256, 0, stream>>>(
        X, wt_ec2, nullptr, 0.0f, AB, nullptr);
    edge_combine<<<PTS, 256, 0, stream>>>(
        AB, knn, g2_gamma, g2_beta, g2_mean, g2_var, Y, out + 16384);

    gemm_bf16<256, 256, 1><<<dim3(PTS / 64, 4), 256, 0, stream>>>(
        Y, wt_q1, q_b1, 0.01f, X, nullptr);
    gemm_bf16<256, 64, 1><<<dim3(PTS / 64, 1), 256, 0, stream>>>(
        X, wt_q2, q_b2, 0.01f, Z, nullptr);
    q3_kernel<<<PTS / 256, 256, 0, stream>>>(Z, q_w3, q_b3, out);
}

// Round 11
// 261.434 us; speedup vs baseline: 1.2831x; 1.0010x over previous
//
#include <hip/hip_runtime.h>

// ---------------------------------------------------------------------------
// Refine_moduleGNN: pad+transpose -> gather conv (pipelined v3) -> pre-MLP ->
// 2x EdgeConv -> head. MFMA bf16.
// R10 = 261.7us best. R11: tail GEMMs get KSTEP template -- K staged in 1-2
// LDS rounds instead of 4-5 (fewer stage->barrier->MFMA rounds). Only change.
// ---------------------------------------------------------------------------

typedef __bf16 bf16_t;
typedef bf16_t bf16x2 __attribute__((ext_vector_type(2)));
typedef bf16_t bf16x8 __attribute__((ext_vector_type(8)));
typedef float  f32x4  __attribute__((ext_vector_type(4)));

static constexpr int BATCH = 16;
static constexpr int NPT   = 512;
static constexpr int PTS   = BATCH * NPT;   // 8192
static constexpr int CONVM = PTS * 4;       // 32768 conv rows
static constexpr int CONVK = 4096;          // 256*4*4

// padded image dims (+4 origin)
static constexpr int PY_DIM = 136;
static constexpr size_t IMG_BSTRIDE = (size_t)PY_DIM * PY_DIM * 256;

// ---- workspace layout (bytes) ----
static constexpr size_t OFF_WCONV_OLD = 0;                                // [64][4096] (c,pix)
static constexpr size_t OFF_WCONVP    = OFF_WCONV_OLD + (size_t)64*4096*2;// [64][16][256]
static constexpr size_t OFF_WPRE1     = OFF_WCONVP    + (size_t)64*4096*2;
static constexpr size_t OFF_WPRE2     = OFF_WPRE1     + (size_t)256*320*2;
static constexpr size_t OFF_WEC1      = OFF_WPRE2     + (size_t)256*256*2;
static constexpr size_t OFF_WEC2      = OFF_WEC1      + (size_t)512*256*2;
static constexpr size_t OFF_WQ1       = OFF_WEC2      + (size_t)512*256*2;
static constexpr size_t OFF_WQ2       = OFF_WQ1       + (size_t)256*256*2;
static constexpr size_t OFF_LOCAL     = OFF_WQ2       + (size_t)64*256*2; // [8192][320] bf16
static constexpr size_t OFF_X         = OFF_LOCAL + (size_t)PTS*320*2;
static constexpr size_t OFF_Y         = OFF_X     + (size_t)PTS*256*2;
static constexpr size_t OFF_Z         = OFF_Y     + (size_t)PTS*256*2;    // [8192][64]
// union region: AB bf16 [8192][512] (edgeconv) | imgT (conv phase only)
static constexpr size_t OFF_UNION     = OFF_Z     + (size_t)PTS*64*2;
static constexpr size_t AB_BYTES      = (size_t)PTS*512*2;                 // 8 MB
static constexpr size_t IMGT_BYTES    = (size_t)16*IMG_BSTRIDE*2;          // ~145 MB
static constexpr size_t WS_BASE       = OFF_UNION + AB_BYTES;
static constexpr size_t WS_FULL       = OFF_UNION + IMGT_BYTES;

// ---------------------------------------------------------------------------
// Weight prep
// ---------------------------------------------------------------------------
static constexpr int WP_CONV  = 64*4096;
static constexpr int WP_CONVP = 64*4096;
static constexpr int WP_PRE1 = 256*320;
static constexpr int WP_PRE2 = 256*256;
static constexpr int WP_EC   = 512*256;
static constexpr int WP_Q1   = 256*256;
static constexpr int WP_Q2   = 64*256;
static constexpr int WP_TOTAL = WP_CONV + WP_CONVP + WP_PRE1 + WP_PRE2 + 2*WP_EC + WP_Q1 + WP_Q2;

__global__ __launch_bounds__(256) void wprep_kernel(
    const float* __restrict__ conv_w, const float* __restrict__ pre_w1,
    const float* __restrict__ pre_w2, const float* __restrict__ g1_w,
    const float* __restrict__ g2_w,   const float* __restrict__ q_w1,
    const float* __restrict__ q_w2,
    bf16_t* __restrict__ wt_conv, bf16_t* __restrict__ wt_convp,
    bf16_t* __restrict__ wt_pre1,
    bf16_t* __restrict__ wt_pre2, bf16_t* __restrict__ wt_ec1,
    bf16_t* __restrict__ wt_ec2,  bf16_t* __restrict__ wt_q1,
    bf16_t* __restrict__ wt_q2)
{
    int i = blockIdx.x * 256 + threadIdx.x;
    if (i >= WP_TOTAL) return;
    if (i < WP_CONV) { wt_conv[i] = (bf16_t)conv_w[i]; return; }
    i -= WP_CONV;
    if (i < WP_CONVP) {   // [o][pix][c] <- conv_w[(o*256+c)*16 + pix]
        const int o = i >> 12, pix = (i >> 8) & 15, c = i & 255;
        wt_convp[i] = (bf16_t)conv_w[((o * 256 + c) << 4) + pix]; return; }
    i -= WP_CONVP;
    if (i < WP_PRE1) { int n = i / 320, k = i - n * 320;
        wt_pre1[i] = (bf16_t)pre_w1[k * 256 + n]; return; }
    i -= WP_PRE1;
    if (i < WP_PRE2) { int n = i >> 8, k = i & 255;
        wt_pre2[i] = (bf16_t)pre_w2[k * 256 + n]; return; }
    i -= WP_PRE2;
    if (i < WP_EC) { int n = i >> 8, k = i & 255;
        wt_ec1[i] = (bf16_t)(n < 256 ? g1_w[n * 512 + k] : g1_w[(n - 256) * 512 + 256 + k]);
        return; }
    i -= WP_EC;
    if (i < WP_EC) { int n = i >> 8, k = i & 255;
        wt_ec2[i] = (bf16_t)(n < 256 ? g2_w[n * 512 + k] : g2_w[(n - 256) * 512 + 256 + k]);
        return; }
    i -= WP_EC;
    if (i < WP_Q1) { int n = i >> 8, k = i & 255;
        wt_q1[i] = (bf16_t)q_w1[k * 256 + n]; return; }
    i -= WP_Q1;
    { int n = i >> 8, k = i & 255;
        wt_q2[i] = (bf16_t)q_w2[k * 64 + n]; }
}

// ---------------------------------------------------------------------------
// Border zero for padded imgT (verified R2)
// ---------------------------------------------------------------------------
static constexpr int PAD_THREADS = 16 * 2112 * 32;

__global__ __launch_bounds__(256) void pad_border(bf16_t* __restrict__ imgT)
{
    const int idx = blockIdx.x * 256 + threadIdx.x;
    if (idx >= PAD_THREADS) return;
    const int t = idx & 31;
    int pi = idx >> 5;
    const int b = pi / 2112; pi -= b * 2112;
    int y, x;
    if (pi < 544)      { y = pi / 136;              x = pi % 136; }
    else if (pi < 1088){ int j = pi - 544; y = 132 + j / 136; x = j % 136; }
    else { int j = pi - 1088; y = 4 + (j >> 3); int k = j & 7; x = (k < 4) ? k : (128 + k); }
    const uint4 z = {0, 0, 0, 0};
    ((uint4*)(imgT + ((size_t)(b * PY_DIM + y) * PY_DIM + x) * 256))[t] = z;
}

// ---------------------------------------------------------------------------
// Image transpose: img[b][c][y][x] f32 -> imgT[b][y+4][x+4][c] bf16 (verified)
// ---------------------------------------------------------------------------
__global__ __launch_bounds__(256) void transpose_img(
    const float* __restrict__ img, bf16_t* __restrict__ imgT)
{
    __shared__ float T[64][65];
    const int bid = blockIdx.x;
    const int cc = bid & 3;
    const int xh = (bid >> 2) & 1;
    const int y  = (bid >> 3) & 127;
    const int b  = bid >> 10;
    const int t = threadIdx.x;
    const int x0 = xh * 64, c0 = cc * 64;
    {
        const int px = t & 63, cr = t >> 6;
        const float* src = img + ((size_t)(b * 256 + c0 + cr) * 128 + y) * 128 + x0 + px;
        #pragma unroll
        for (int i = 0; i < 16; ++i)
            T[cr + i * 4][px] = src[(size_t)i * 4 * 16384];
    }
    __syncthreads();
    {
        const int cl2 = (t & 31) * 2, pr = t >> 5;
        bf16_t* dst = imgT + ((size_t)(b * PY_DIM + y + 4) * PY_DIM + x0 + 4) * 256 + c0 + cl2;
        #pragma unroll
        for (int i = 0; i < 8; ++i) {
            const int pxl = pr + i * 8;
            bf16x2 w;
            w[0] = (bf16_t)T[cl2][pxl];
            w[1] = (bf16_t)T[cl2 + 1][pxl];
            *(bf16x2*)(dst + (size_t)pxl * 256) = w;
        }
    }
}

// ---------------------------------------------------------------------------
// Conv-gather GEMM v3p (R10): register-prefetch pipeline.
// ---------------------------------------------------------------------------
__global__ __launch_bounds__(256) void conv_gather_gemm3p(
    const bf16_t* __restrict__ imgT,    // [16][136][136][256], +4 origin
    const bf16_t* __restrict__ Wc,      // [64][16][256]
    const float* __restrict__ conv_b, const float* __restrict__ roi,
    const int* __restrict__ px, const int* __restrict__ py,
    bf16_t* __restrict__ local)
{
    __shared__ bf16_t As[32][136];
    __shared__ bf16_t Bs[64][136];
    const int tid = threadIdx.x, lane = tid & 63, wave = tid >> 6;
    const int wm = wave & 1, wn = wave >> 1;
    const int row0 = blockIdx.x * 32;

    const int ra = tid >> 3, seg = tid & 7;
    const int r = row0 + ra, corner = r & 3, pnt = r >> 2, b = pnt >> 9;
    const int oy = 2 * py[pnt] + (corner & 1) * 4 + 1;
    const int ox = 2 * px[pnt] + ((corner >> 1) & 1) * 4 + 1;
    const bf16_t* imgb = imgT + (size_t)b * IMG_BSTRIDE;
    const int rb = tid >> 2, sq = tid & 3;
    const bf16_t* wrow = Wc + (size_t)rb * 4096 + sq * 8;

    uint4 a0, a1, b0, b1, b2, b3;
    {
        const bf16_t* srcA = imgb + ((size_t)((oy) * PY_DIM + ox)) * 256 + seg * 16;
        a0 = *(const uint4*)srcA;
        a1 = *(const uint4*)(srcA + 8);
        const bf16_t* srcB = wrow;
        b0 = *(const uint4*)srcB;
        b1 = *(const uint4*)(srcB + 32);
        b2 = *(const uint4*)(srcB + 64);
        b3 = *(const uint4*)(srcB + 96);
    }

    f32x4 acc[2] = {};
    #pragma unroll 1
    for (int s = 0; s < 32; ++s) {
        __syncthreads();
        *(uint4*)&As[ra][seg * 16]     = a0;
        *(uint4*)&As[ra][seg * 16 + 8] = a1;
        *(uint4*)&Bs[rb][sq * 8]       = b0;
        *(uint4*)&Bs[rb][sq * 8 + 32]  = b1;
        *(uint4*)&Bs[rb][sq * 8 + 64]  = b2;
        *(uint4*)&Bs[rb][sq * 8 + 96]  = b3;
        if (s < 31) {
            const int sn = s + 1;
            const int pix = sn >> 1, h = sn & 1;
            const int iy = oy + (pix >> 2), ix = ox + (pix & 3);
            const bf16_t* srcA = imgb + ((size_t)(iy * PY_DIM + ix)) * 256 + h * 128 + seg * 16;
            a0 = *(const uint4*)srcA;
            a1 = *(const uint4*)(srcA + 8);
            const bf16_t* srcB = wrow + pix * 256 + h * 128;
            b0 = *(const uint4*)srcB;
            b1 = *(const uint4*)(srcB + 32);
            b2 = *(const uint4*)(srcB + 64);
            b3 = *(const uint4*)(srcB + 96);
        }
        __syncthreads();
        #pragma unroll
        for (int kk = 0; kk < 128; kk += 32) {
            const int kf = kk + ((lane >> 4) << 3);
            bf16x8 a  = *(const bf16x8*)&As[wm * 16 + (lane & 15)][kf];
            bf16x8 bb0 = *(const bf16x8*)&Bs[wn * 32 + (lane & 15)][kf];
            bf16x8 bb1 = *(const bf16x8*)&Bs[wn * 32 + 16 + (lane & 15)][kf];
            acc[0] = __builtin_amdgcn_mfma_f32_16x16x32_bf16(a, bb0, acc[0], 0, 0, 0);
            acc[1] = __builtin_amdgcn_mfma_f32_16x16x32_bf16(a, bb1, acc[1], 0, 0, 0);
        }
    }
    const int crow = (lane >> 4) << 2;
    const int ccol = lane & 15;
    #pragma unroll
    for (int j = 0; j < 2; ++j) {
        const int o = wn * 32 + j * 16 + ccol;
        const float bv = conv_b[o];
        #pragma unroll
        for (int rg = 0; rg < 4; ++rg) {
            const int gr = row0 + wm * 16 + crow + rg;
            const int cn = gr & 3;
            const int pp = gr >> 2;
            const float v = (acc[j][rg] + bv) * roi[pp];
            local[(size_t)pp * 320 + cn * 64 + o] = (bf16_t)v;
        }
    }
}

// ---------------------------------------------------------------------------
// Conv-gather GEMM v1 (fallback for small ws): scattered f32.
// ---------------------------------------------------------------------------
__global__ __launch_bounds__(256) void conv_gather_gemm(
    const float* __restrict__ img, const bf16_t* __restrict__ Wc,
    const float* __restrict__ conv_b, const float* __restrict__ roi,
    const int* __restrict__ px, const int* __restrict__ py,
    bf16_t* __restrict__ local)
{
    __shared__ bf16_t As[64][72];
    __shared__ bf16_t Bs[64][72];
    const int tid = threadIdx.x;
    const int lane = tid & 63;
    const int wave = tid >> 6;
    const int wm = wave & 1, wn = wave >> 1;
    const int row0 = blockIdx.x * 64;
    const int sm = tid >> 2;
    const int cq = tid & 3;
    const int r = row0 + sm;
    const int corner = r & 3;
    const int pnt = r >> 2;
    const int b = pnt >> 9;
    const int oy = 2 * py[pnt] + (corner & 1) * 4;
    const int ox = 2 * px[pnt] + ((corner >> 1) & 1) * 4;
    const int iy0 = oy - 3, ix0 = ox - 3;
    const float* imgb = img + (size_t)b * (256 * 128 * 128);

    f32x4 acc[2][2] = {};
    for (int kt = 0; kt < CONVK; kt += 64) {
        {
            const int c = (kt >> 4) + cq;
            const float* ip = imgb + (size_t)c * (128 * 128);
            alignas(16) bf16_t vals[16];
            #pragma unroll
            for (int ky = 0; ky < 4; ++ky) {
                const int iy = iy0 + ky;
                const bool yok = (unsigned)iy < 128u;
                #pragma unroll
                for (int kx = 0; kx < 4; ++kx) {
                    const int ix = ix0 + kx;
                    float v = (yok && (unsigned)ix < 128u) ? ip[iy * 128 + ix] : 0.0f;
                    vals[ky * 4 + kx] = (bf16_t)v;
                }
            }
            *(uint4*)&As[sm][cq * 16]     = *(const uint4*)&vals[0];
            *(uint4*)&As[sm][cq * 16 + 8] = *(const uint4*)&vals[8];
        }
        {
            const bf16_t* src = Wc + (size_t)sm * CONVK + kt + cq * 16;
            *(uint4*)&Bs[sm][cq * 16]     = *(const uint4*)src;
            *(uint4*)&Bs[sm][cq * 16 + 8] = *(const uint4*)(src + 8);
        }
        __syncthreads();
        #pragma unroll
        for (int kk = 0; kk < 64; kk += 32) {
            const int kf = kk + ((lane >> 4) << 3);
            bf16x8 a0 = *(const bf16x8*)&As[wm * 32 + (lane & 15)][kf];
            bf16x8 a1 = *(const bf16x8*)&As[wm * 32 + 16 + (lane & 15)][kf];
            bf16x8 b0 = *(const bf16x8*)&Bs[wn * 32 + (lane & 15)][kf];
            bf16x8 b1 = *(const bf16x8*)&Bs[wn * 32 + 16 + (lane & 15)][kf];
            acc[0][0] = __builtin_amdgcn_mfma_f32_16x16x32_bf16(a0, b0, acc[0][0], 0, 0, 0);
            acc[0][1] = __builtin_amdgcn_mfma_f32_16x16x32_bf16(a0, b1, acc[0][1], 0, 0, 0);
            acc[1][0] = __builtin_amdgcn_mfma_f32_16x16x32_bf16(a1, b0, acc[1][0], 0, 0, 0);
            acc[1][1] = __builtin_amdgcn_mfma_f32_16x16x32_bf16(a1, b1, acc[1][1], 0, 0, 0);
        }
        __syncthreads();
    }
    const int crow = (lane >> 4) << 2;
    const int ccol = lane & 15;
    #pragma unroll
    for (int i = 0; i < 2; ++i) {
        #pragma unroll
        for (int j = 0; j < 2; ++j) {
            const int o = wn * 32 + j * 16 + ccol;
            const float bv = conv_b[o];
            #pragma unroll
            for (int rg = 0; rg < 4; ++rg) {
                const int gr = row0 + wm * 32 + i * 16 + crow + rg;
                const int cn = gr & 3;
                const int pp = gr >> 2;
                const float v = (acc[i][j][rg] + bv) * roi[pp];
                local[(size_t)pp * 320 + cn * 64 + o] = (bf16_t)v;
            }
        }
    }
}

// ---------------------------------------------------------------------------
// graph_feat fill
// ---------------------------------------------------------------------------
__global__ __launch_bounds__(256) void graph_fill(
    const float* __restrict__ g, bf16_t* __restrict__ local)
{
    const int e = blockIdx.x * 256 + threadIdx.x;
    const int j = e & 63, p = e >> 6;
    const int b = p >> 9, n = p & 511;
    local[(size_t)p * 320 + 256 + j] = (bf16_t)g[((size_t)(b * 64 + j) << 9) + n];
}

// ---------------------------------------------------------------------------
// Generic MFMA GEMM with KSTEP: C[8192][N] = A[8192][K] @ Bt[N][K]^T.
// K staged in K/KSTEP rounds (1-2 instead of 4-5) -- fewer barrier rounds.
// ---------------------------------------------------------------------------
template<int K, int KSTEP, int N, int ACT>
__global__ __launch_bounds__(256) void gemm_bf16(
    const bf16_t* __restrict__ A, const bf16_t* __restrict__ Bt,
    const float* __restrict__ bias, float slope,
    bf16_t* __restrict__ outB, float* __restrict__ outF)
{
    __shared__ bf16_t As[64][KSTEP + 8];
    __shared__ bf16_t Bs[64][KSTEP + 8];
    const int tid = threadIdx.x;
    const int lane = tid & 63;
    const int wave = tid >> 6;
    const int wm = wave & 1, wn = wave >> 1;
    const int row0 = blockIdx.x * 64;
    const int col0 = blockIdx.y * 64;
    const int sm = tid >> 2;
    const int sq = (tid & 3) * (KSTEP / 4);   // element offset of this task

    f32x4 acc[2][2] = {};
    #pragma unroll 1
    for (int kt = 0; kt < K; kt += KSTEP) {
        {
            const bf16_t* src = A + (size_t)(row0 + sm) * K + kt + sq;
            #pragma unroll
            for (int i = 0; i < KSTEP / 32; ++i)
                *(uint4*)&As[sm][sq + i * 8] = *(const uint4*)(src + i * 8);
        }
        {
            const bf16_t* src = Bt + (size_t)(col0 + sm) * K + kt + sq;
            #pragma unroll
            for (int i = 0; i < KSTEP / 32; ++i)
                *(uint4*)&Bs[sm][sq + i * 8] = *(const uint4*)(src + i * 8);
        }
        __syncthreads();
        #pragma unroll
        for (int kk = 0; kk < KSTEP; kk += 32) {
            const int kf = kk + ((lane >> 4) << 3);
            bf16x8 a0 = *(const bf16x8*)&As[wm * 32 + (lane & 15)][kf];
            bf16x8 a1 = *(const bf16x8*)&As[wm * 32 + 16 + (lane & 15)][kf];
            bf16x8 b0 = *(const bf16x8*)&Bs[wn * 32 + (lane & 15)][kf];
            bf16x8 b1 = *(const bf16x8*)&Bs[wn * 32 + 16 + (lane & 15)][kf];
            acc[0][0] = __builtin_amdgcn_mfma_f32_16x16x32_bf16(a0, b0, acc[0][0], 0, 0, 0);
            acc[0][1] = __builtin_amdgcn_mfma_f32_16x16x32_bf16(a0, b1, acc[0][1], 0, 0, 0);
            acc[1][0] = __builtin_amdgcn_mfma_f32_16x16x32_bf16(a1, b0, acc[1][0], 0, 0, 0);
            acc[1][1] = __builtin_amdgcn_mfma_f32_16x16x32_bf16(a1, b1, acc[1][1], 0, 0, 0);
        }
        __syncthreads();
    }
    const int crow = (lane >> 4) << 2;
    const int ccol = lane & 15;
    #pragma unroll
    for (int i = 0; i < 2; ++i) {
        #pragma unroll
        for (int j = 0; j < 2; ++j) {
            const int gcol = col0 + wn * 32 + j * 16 + ccol;
            const float bv = bias ? bias[gcol] : 0.0f;
            #pragma unroll
            for (int rg = 0; rg < 4; ++rg) {
                const int grow = row0 + wm * 32 + i * 16 + crow + rg;
                float v = acc[i][j][rg] + bv;
                if (ACT == 1) v = v >= 0.0f ? v : slope * v;
                if (outB) outB[(size_t)grow * N + gcol] = (bf16_t)v;
                if (outF) outF[(size_t)grow * N + gcol] = v;
            }
        }
    }
}

// ---------------------------------------------------------------------------
// EdgeConv combine (bf16 AB input)
// ---------------------------------------------------------------------------
__global__ __launch_bounds__(256) void edge_combine(
    const bf16_t* __restrict__ AB, const int* __restrict__ knn,
    const float* __restrict__ gamma, const float* __restrict__ beta,
    const float* __restrict__ mean,  const float* __restrict__ var,
    bf16_t* __restrict__ outB, float* __restrict__ outT)
{
    const int p = blockIdx.x;
    const int b = p >> 9, n = p & 511;
    const int o = threadIdx.x;
    const float sc = gamma[o] / sqrtf(var[o] + 1e-5f);
    const float sh = beta[o] - mean[o] * sc;
    const bf16_t* rowp = AB + (size_t)p * 512;
    const float d = (float)rowp[256 + o] - (float)rowp[o];
    const bf16_t* batch = AB + ((size_t)(b << 9)) * 512;
    float m = -3.4e38f;
    #pragma unroll 4
    for (int k = 0; k < 20; ++k) {
        const int q = knn[n * 20 + k];
        const float v = (float)batch[(size_t)q * 512 + o] + d;
        float y = v * sc + sh;
        y = y >= 0.0f ? y : 0.2f * y;
        m = fmaxf(m, y);
    }
    outB[(size_t)p * 256 + o] = (bf16_t)m;
    if (outT) outT[((size_t)(b * 256 + o) << 9) + n] = m;
}

// ---------------------------------------------------------------------------
// Head final layer
// ---------------------------------------------------------------------------
__global__ __launch_bounds__(256) void q3_kernel(
    const bf16_t* __restrict__ Z, const float* __restrict__ w3,
    const float* __restrict__ b3, float* __restrict__ out)
{
    const int p = blockIdx.x * 256 + threadIdx.x;
    const int b = p >> 9, n = p & 511;
    const bf16_t* q = Z + (size_t)p * 64;
    float s0 = b3[0], s1 = b3[1];
    #pragma unroll
    for (int c = 0; c < 64; ++c) {
        const float v = (float)q[c];
        s0 += v * w3[2 * c];
        s1 += v * w3[2 * c + 1];
    }
    out[(size_t)(b * 2 + 0) * 512 + n] = s0;
    out[(size_t)(b * 2 + 1) * 512 + n] = s1;
}

// ---------------------------------------------------------------------------
extern "C" void kernel_launch(void* const* d_in, const int* in_sizes, int n_in,
                              void* d_out, int out_size, void* d_ws, size_t ws_size,
                              hipStream_t stream)
{
    const float* img      = (const float*)d_in[0];
    const float* graph    = (const float*)d_in[1];
    const float* roi      = (const float*)d_in[2];
    const int*   px       = (const int*)d_in[3];
    const int*   py       = (const int*)d_in[4];
    const int*   knn      = (const int*)d_in[5];
    const float* conv_w   = (const float*)d_in[6];
    const float* conv_b   = (const float*)d_in[7];
    const float* pre_w1   = (const float*)d_in[8];
    const float* pre_b1   = (const float*)d_in[9];
    const float* pre_w2   = (const float*)d_in[10];
    const float* pre_b2   = (const float*)d_in[11];
    const float* g1_w     = (const float*)d_in[12];
    const float* g1_gamma = (const float*)d_in[13];
    const float* g1_beta  = (const float*)d_in[14];
    const float* g1_mean  = (const float*)d_in[15];
    const float* g1_var   = (const float*)d_in[16];
    const float* g2_w     = (const float*)d_in[17];
    const float* g2_gamma = (const float*)d_in[18];
    const float* g2_beta  = (const float*)d_in[19];
    const float* g2_mean  = (const float*)d_in[20];
    const float* g2_var   = (const float*)d_in[21];
    const float* q_w1     = (const float*)d_in[22];
    const float* q_b1     = (const float*)d_in[23];
    const float* q_w2     = (const float*)d_in[24];
    const float* q_b2     = (const float*)d_in[25];
    const float* q_w3     = (const float*)d_in[26];
    const float* q_b3     = (const float*)d_in[27];
    float* out = (float*)d_out;

    if (ws_size < WS_BASE) return;

    char* ws = (char*)d_ws;
    bf16_t* wt_conv  = (bf16_t*)(ws + OFF_WCONV_OLD);
    bf16_t* wt_convp = (bf16_t*)(ws + OFF_WCONVP);
    bf16_t* wt_pre1  = (bf16_t*)(ws + OFF_WPRE1);
    bf16_t* wt_pre2  = (bf16_t*)(ws + OFF_WPRE2);
    bf16_t* wt_ec1   = (bf16_t*)(ws + OFF_WEC1);
    bf16_t* wt_ec2   = (bf16_t*)(ws + OFF_WEC2);
    bf16_t* wt_q1    = (bf16_t*)(ws + OFF_WQ1);
    bf16_t* wt_q2    = (bf16_t*)(ws + OFF_WQ2);
    bf16_t* local    = (bf16_t*)(ws + OFF_LOCAL);
    bf16_t* X        = (bf16_t*)(ws + OFF_X);
    bf16_t* Y        = (bf16_t*)(ws + OFF_Y);
    bf16_t* Z        = (bf16_t*)(ws + OFF_Z);
    bf16_t* AB       = (bf16_t*)(ws + OFF_UNION);
    bf16_t* imgT     = (bf16_t*)(ws + OFF_UNION);

    const bool big = ws_size >= WS_FULL;

    wprep_kernel<<<(WP_TOTAL + 255) / 256, 256, 0, stream>>>(
        conv_w, pre_w1, pre_w2, g1_w, g2_w, q_w1, q_w2,
        wt_conv, wt_convp, wt_pre1, wt_pre2, wt_ec1, wt_ec2, wt_q1, wt_q2);

    if (big) {
        pad_border<<<(PAD_THREADS + 255) / 256, 256, 0, stream>>>(imgT);
        transpose_img<<<16 * 128 * 2 * 4, 256, 0, stream>>>(img, imgT);
        conv_gather_gemm3p<<<CONVM / 32, 256, 0, stream>>>(
            imgT, wt_convp, conv_b, roi, px, py, local);
    } else {
        conv_gather_gemm<<<CONVM / 64, 256, 0, stream>>>(
            img, wt_conv, conv_b, roi, px, py, local);
    }

    graph_fill<<<(PTS * 64) / 256, 256, 0, stream>>>(graph, local);

    gemm_bf16<320, 160, 256, 1><<<dim3(PTS / 64, 4), 256, 0, stream>>>(
        local, wt_pre1, pre_b1, 0.01f, X, nullptr);
    gemm_bf16<256, 256, 256, 1><<<dim3(PTS / 64, 4), 256, 0, stream>>>(
        X, wt_pre2, pre_b2, 0.01f, Y, nullptr);

    gemm_bf16<256, 128, 512, 0><<<dim3(PTS / 64, 8), 256, 0, stream>>>(
        Y, wt_ec1, nullptr, 0.0f, AB, nullptr);
    edge_combine<<<PTS, 256, 0, stream>>>(
        AB, knn, g1_gamma, g1_beta, g1_mean, g1_var, X, nullptr);

    gemm_bf16<256, 128, 512, 0><<<dim3(PTS / 64, 8), 256, 0, stream>>>(
        X, wt_ec2, nullptr, 0.0f, AB, nullptr);
    edge_combine<<<PTS, 256, 0, stream>>>(
        AB, knn, g2_gamma, g2_beta, g2_mean, g2_var, Y, out + 16384);

    gemm_bf16<256, 256, 256, 1><<<dim3(PTS / 64, 4), 256, 0, stream>>>(
        Y, wt_q1, q_b1, 0.01f, X, nullptr);
    gemm_bf16<256, 256, 64, 1><<<dim3(PTS / 64, 1), 256, 0, stream>>>(
        X, wt_q2, q_b2, 0.01f, Z, nullptr);
    q3_kernel<<<PTS / 256, 256, 0, stream>>>(Z, q_w3, q_b3, out);
}

// Round 12
// 253.098 us; speedup vs baseline: 1.3253x; 1.0329x over previous
//
#include <hip/hip_runtime.h>

// ---------------------------------------------------------------------------
// Refine_moduleGNN: pad+transpose -> gather conv (pipelined v3) -> pre-MLP ->
// 2x EdgeConv -> head. MFMA bf16.
// R11 = 261.4us best. R12: (a) 2-batch-group transpose/conv interleave for
// L3 residency of imgT; (b) pad folded into wprep; (c) graph_fill folded
// into conv epilogue; (d) q2+q3 fused.
// ---------------------------------------------------------------------------

typedef __bf16 bf16_t;
typedef bf16_t bf16x2 __attribute__((ext_vector_type(2)));
typedef bf16_t bf16x8 __attribute__((ext_vector_type(8)));
typedef float  f32x4  __attribute__((ext_vector_type(4)));

static constexpr int BATCH = 16;
static constexpr int NPT   = 512;
static constexpr int PTS   = BATCH * NPT;   // 8192
static constexpr int CONVM = PTS * 4;       // 32768 conv rows
static constexpr int CONVK = 4096;          // 256*4*4

// padded image dims (+4 origin)
static constexpr int PY_DIM = 136;
static constexpr size_t IMG_BSTRIDE = (size_t)PY_DIM * PY_DIM * 256;

// ---- workspace layout (bytes) ----
static constexpr size_t OFF_WCONV_OLD = 0;                                // [64][4096] (c,pix)
static constexpr size_t OFF_WCONVP    = OFF_WCONV_OLD + (size_t)64*4096*2;// [64][16][256]
static constexpr size_t OFF_WPRE1     = OFF_WCONVP    + (size_t)64*4096*2;
static constexpr size_t OFF_WPRE2     = OFF_WPRE1     + (size_t)256*320*2;
static constexpr size_t OFF_WEC1      = OFF_WPRE2     + (size_t)256*256*2;
static constexpr size_t OFF_WEC2      = OFF_WEC1      + (size_t)512*256*2;
static constexpr size_t OFF_WQ1       = OFF_WEC2      + (size_t)512*256*2;
static constexpr size_t OFF_WQ2       = OFF_WQ1       + (size_t)256*256*2;
static constexpr size_t OFF_LOCAL     = OFF_WQ2       + (size_t)64*256*2; // [8192][320] bf16
static constexpr size_t OFF_X         = OFF_LOCAL + (size_t)PTS*320*2;
static constexpr size_t OFF_Y         = OFF_X     + (size_t)PTS*256*2;
static constexpr size_t OFF_Z         = OFF_Y     + (size_t)PTS*256*2;    // [8192][64]
// union region: AB bf16 [8192][512] (edgeconv) | imgT (conv phase only)
static constexpr size_t OFF_UNION     = OFF_Z     + (size_t)PTS*64*2;
static constexpr size_t AB_BYTES      = (size_t)PTS*512*2;                 // 8 MB
static constexpr size_t IMGT_BYTES    = (size_t)16*IMG_BSTRIDE*2;          // ~145 MB
static constexpr size_t WS_BASE       = OFF_UNION + AB_BYTES;
static constexpr size_t WS_FULL       = OFF_UNION + IMGT_BYTES;

// ---------------------------------------------------------------------------
// Weight prep + (fused) border zero for padded imgT
// ---------------------------------------------------------------------------
static constexpr int WP_CONV  = 64*4096;
static constexpr int WP_CONVP = 64*4096;
static constexpr int WP_PRE1 = 256*320;
static constexpr int WP_PRE2 = 256*256;
static constexpr int WP_EC   = 512*256;
static constexpr int WP_Q1   = 256*256;
static constexpr int WP_Q2   = 64*256;
static constexpr int WP_TOTAL = WP_CONV + WP_CONVP + WP_PRE1 + WP_PRE2 + 2*WP_EC + WP_Q1 + WP_Q2;
static constexpr int PAD_THREADS = 16 * 2112 * 32;

__global__ __launch_bounds__(256) void wprep_pad_kernel(
    const float* __restrict__ conv_w, const float* __restrict__ pre_w1,
    const float* __restrict__ pre_w2, const float* __restrict__ g1_w,
    const float* __restrict__ g2_w,   const float* __restrict__ q_w1,
    const float* __restrict__ q_w2,
    bf16_t* __restrict__ wt_conv, bf16_t* __restrict__ wt_convp,
    bf16_t* __restrict__ wt_pre1,
    bf16_t* __restrict__ wt_pre2, bf16_t* __restrict__ wt_ec1,
    bf16_t* __restrict__ wt_ec2,  bf16_t* __restrict__ wt_q1,
    bf16_t* __restrict__ wt_q2,   bf16_t* __restrict__ imgT)
{
    int i = blockIdx.x * 256 + threadIdx.x;
    if (i >= WP_TOTAL) {
        // ---- pad-border task (verified R2 logic)
        const int idx = i - WP_TOTAL;
        if (idx >= PAD_THREADS || imgT == nullptr) return;
        const int t = idx & 31;
        int pi = idx >> 5;
        const int b = pi / 2112; pi -= b * 2112;
        int y, x;
        if (pi < 544)      { y = pi / 136;              x = pi % 136; }
        else if (pi < 1088){ int j = pi - 544; y = 132 + j / 136; x = j % 136; }
        else { int j = pi - 1088; y = 4 + (j >> 3); int k = j & 7; x = (k < 4) ? k : (128 + k); }
        const uint4 z = {0, 0, 0, 0};
        ((uint4*)(imgT + ((size_t)(b * PY_DIM + y) * PY_DIM + x) * 256))[t] = z;
        return;
    }
    if (i < WP_CONV) { wt_conv[i] = (bf16_t)conv_w[i]; return; }
    i -= WP_CONV;
    if (i < WP_CONVP) {   // [o][pix][c] <- conv_w[(o*256+c)*16 + pix]
        const int o = i >> 12, pix = (i >> 8) & 15, c = i & 255;
        wt_convp[i] = (bf16_t)conv_w[((o * 256 + c) << 4) + pix]; return; }
    i -= WP_CONVP;
    if (i < WP_PRE1) { int n = i / 320, k = i - n * 320;
        wt_pre1[i] = (bf16_t)pre_w1[k * 256 + n]; return; }
    i -= WP_PRE1;
    if (i < WP_PRE2) { int n = i >> 8, k = i & 255;
        wt_pre2[i] = (bf16_t)pre_w2[k * 256 + n]; return; }
    i -= WP_PRE2;
    if (i < WP_EC) { int n = i >> 8, k = i & 255;
        wt_ec1[i] = (bf16_t)(n < 256 ? g1_w[n * 512 + k] : g1_w[(n - 256) * 512 + 256 + k]);
        return; }
    i -= WP_EC;
    if (i < WP_EC) { int n = i >> 8, k = i & 255;
        wt_ec2[i] = (bf16_t)(n < 256 ? g2_w[n * 512 + k] : g2_w[(n - 256) * 512 + 256 + k]);
        return; }
    i -= WP_EC;
    if (i < WP_Q1) { int n = i >> 8, k = i & 255;
        wt_q1[i] = (bf16_t)q_w1[k * 256 + n]; return; }
    i -= WP_Q1;
    { int n = i >> 8, k = i & 255;
        wt_q2[i] = (bf16_t)q_w2[k * 64 + n]; }
}

// ---------------------------------------------------------------------------
// Image transpose: img[b][c][y][x] f32 -> imgT[b][y+4][x+4][c] bf16.
// b0 selects the 8-batch group (L3-residency interleave).
// ---------------------------------------------------------------------------
__global__ __launch_bounds__(256) void transpose_img(
    const float* __restrict__ img, bf16_t* __restrict__ imgT, int b0)
{
    __shared__ float T[64][65];
    const int bid = blockIdx.x;
    const int cc = bid & 3;
    const int xh = (bid >> 2) & 1;
    const int y  = (bid >> 3) & 127;
    const int b  = b0 + (bid >> 10);
    const int t = threadIdx.x;
    const int x0 = xh * 64, c0 = cc * 64;
    {
        const int px = t & 63, cr = t >> 6;
        const float* src = img + ((size_t)(b * 256 + c0 + cr) * 128 + y) * 128 + x0 + px;
        #pragma unroll
        for (int i = 0; i < 16; ++i)
            T[cr + i * 4][px] = src[(size_t)i * 4 * 16384];
    }
    __syncthreads();
    {
        const int cl2 = (t & 31) * 2, pr = t >> 5;
        bf16_t* dst = imgT + ((size_t)(b * PY_DIM + y + 4) * PY_DIM + x0 + 4) * 256 + c0 + cl2;
        #pragma unroll
        for (int i = 0; i < 8; ++i) {
            const int pxl = pr + i * 8;
            bf16x2 w;
            w[0] = (bf16_t)T[cl2][pxl];
            w[1] = (bf16_t)T[cl2 + 1][pxl];
            *(bf16x2*)(dst + (size_t)pxl * 256) = w;
        }
    }
}

// ---------------------------------------------------------------------------
// Conv-gather GEMM v3p (R10 pipeline) + graph fold-in epilogue.
// row_base selects the batch group.
// ---------------------------------------------------------------------------
__global__ __launch_bounds__(256) void conv_gather_gemm3p(
    const bf16_t* __restrict__ imgT,    // [16][136][136][256], +4 origin
    const bf16_t* __restrict__ Wc,      // [64][16][256]
    const float* __restrict__ conv_b, const float* __restrict__ roi,
    const int* __restrict__ px, const int* __restrict__ py,
    const float* __restrict__ graph,
    bf16_t* __restrict__ local, int row_base)
{
    __shared__ bf16_t As[32][136];
    __shared__ bf16_t Bs[64][136];
    const int tid = threadIdx.x, lane = tid & 63, wave = tid >> 6;
    const int wm = wave & 1, wn = wave >> 1;
    const int row0 = row_base + blockIdx.x * 32;

    const int ra = tid >> 3, seg = tid & 7;
    const int r = row0 + ra, corner = r & 3, pnt = r >> 2, b = pnt >> 9;
    const int oy = 2 * py[pnt] + (corner & 1) * 4 + 1;
    const int ox = 2 * px[pnt] + ((corner >> 1) & 1) * 4 + 1;
    const bf16_t* imgb = imgT + (size_t)b * IMG_BSTRIDE;
    const int rb = tid >> 2, sq = tid & 3;
    const bf16_t* wrow = Wc + (size_t)rb * 4096 + sq * 8;

    uint4 a0, a1, b0, b1, b2, b3;
    {
        const bf16_t* srcA = imgb + ((size_t)((oy) * PY_DIM + ox)) * 256 + seg * 16;
        a0 = *(const uint4*)srcA;
        a1 = *(const uint4*)(srcA + 8);
        const bf16_t* srcB = wrow;
        b0 = *(const uint4*)srcB;
        b1 = *(const uint4*)(srcB + 32);
        b2 = *(const uint4*)(srcB + 64);
        b3 = *(const uint4*)(srcB + 96);
    }

    f32x4 acc[2] = {};
    #pragma unroll 1
    for (int s = 0; s < 32; ++s) {
        __syncthreads();
        *(uint4*)&As[ra][seg * 16]     = a0;
        *(uint4*)&As[ra][seg * 16 + 8] = a1;
        *(uint4*)&Bs[rb][sq * 8]       = b0;
        *(uint4*)&Bs[rb][sq * 8 + 32]  = b1;
        *(uint4*)&Bs[rb][sq * 8 + 64]  = b2;
        *(uint4*)&Bs[rb][sq * 8 + 96]  = b3;
        if (s < 31) {
            const int sn = s + 1;
            const int pix = sn >> 1, h = sn & 1;
            const int iy = oy + (pix >> 2), ix = ox + (pix & 3);
            const bf16_t* srcA = imgb + ((size_t)(iy * PY_DIM + ix)) * 256 + h * 128 + seg * 16;
            a0 = *(const uint4*)srcA;
            a1 = *(const uint4*)(srcA + 8);
            const bf16_t* srcB = wrow + pix * 256 + h * 128;
            b0 = *(const uint4*)srcB;
            b1 = *(const uint4*)(srcB + 32);
            b2 = *(const uint4*)(srcB + 64);
            b3 = *(const uint4*)(srcB + 96);
        }
        __syncthreads();
        #pragma unroll
        for (int kk = 0; kk < 128; kk += 32) {
            const int kf = kk + ((lane >> 4) << 3);
            bf16x8 a  = *(const bf16x8*)&As[wm * 16 + (lane & 15)][kf];
            bf16x8 bb0 = *(const bf16x8*)&Bs[wn * 32 + (lane & 15)][kf];
            bf16x8 bb1 = *(const bf16x8*)&Bs[wn * 32 + 16 + (lane & 15)][kf];
            acc[0] = __builtin_amdgcn_mfma_f32_16x16x32_bf16(a, bb0, acc[0], 0, 0, 0);
            acc[1] = __builtin_amdgcn_mfma_f32_16x16x32_bf16(a, bb1, acc[1], 0, 0, 0);
        }
    }
    const int crow = (lane >> 4) << 2;
    const int ccol = lane & 15;
    #pragma unroll
    for (int j = 0; j < 2; ++j) {
        const int o = wn * 32 + j * 16 + ccol;
        const float bv = conv_b[o];
        #pragma unroll
        for (int rg = 0; rg < 4; ++rg) {
            const int gr = row0 + wm * 16 + crow + rg;
            const int cn = gr & 3;
            const int pp = gr >> 2;
            const float v = (acc[j][rg] + bv) * roi[pp];
            local[(size_t)pp * 320 + cn * 64 + o] = (bf16_t)v;
        }
    }
    // ---- graph fold-in: 8 points of this block, 2 channels per thread
    {
        const int pt = (row0 >> 2) + (tid >> 5);
        const int ch = (tid & 31) * 2;
        const int bb = pt >> 9, nn = pt & 511;
        const float* gsrc = graph + (((size_t)bb * 64) << 9) + nn;
        local[(size_t)pt * 320 + 256 + ch]     = (bf16_t)gsrc[(size_t)ch << 9];
        local[(size_t)pt * 320 + 256 + ch + 1] = (bf16_t)gsrc[(size_t)(ch + 1) << 9];
    }
}

// ---------------------------------------------------------------------------
// Conv-gather GEMM v1 (fallback for small ws): scattered f32.
// ---------------------------------------------------------------------------
__global__ __launch_bounds__(256) void conv_gather_gemm(
    const float* __restrict__ img, const bf16_t* __restrict__ Wc,
    const float* __restrict__ conv_b, const float* __restrict__ roi,
    const int* __restrict__ px, const int* __restrict__ py,
    bf16_t* __restrict__ local)
{
    __shared__ bf16_t As[64][72];
    __shared__ bf16_t Bs[64][72];
    const int tid = threadIdx.x;
    const int lane = tid & 63;
    const int wave = tid >> 6;
    const int wm = wave & 1, wn = wave >> 1;
    const int row0 = blockIdx.x * 64;
    const int sm = tid >> 2;
    const int cq = tid & 3;
    const int r = row0 + sm;
    const int corner = r & 3;
    const int pnt = r >> 2;
    const int b = pnt >> 9;
    const int oy = 2 * py[pnt] + (corner & 1) * 4;
    const int ox = 2 * px[pnt] + ((corner >> 1) & 1) * 4;
    const int iy0 = oy - 3, ix0 = ox - 3;
    const float* imgb = img + (size_t)b * (256 * 128 * 128);

    f32x4 acc[2][2] = {};
    for (int kt = 0; kt < CONVK; kt += 64) {
        {
            const int c = (kt >> 4) + cq;
            const float* ip = imgb + (size_t)c * (128 * 128);
            alignas(16) bf16_t vals[16];
            #pragma unroll
            for (int ky = 0; ky < 4; ++ky) {
                const int iy = iy0 + ky;
                const bool yok = (unsigned)iy < 128u;
                #pragma unroll
                for (int kx = 0; kx < 4; ++kx) {
                    const int ix = ix0 + kx;
                    float v = (yok && (unsigned)ix < 128u) ? ip[iy * 128 + ix] : 0.0f;
                    vals[ky * 4 + kx] = (bf16_t)v;
                }
            }
            *(uint4*)&As[sm][cq * 16]     = *(const uint4*)&vals[0];
            *(uint4*)&As[sm][cq * 16 + 8] = *(const uint4*)&vals[8];
        }
        {
            const bf16_t* src = Wc + (size_t)sm * CONVK + kt + cq * 16;
            *(uint4*)&Bs[sm][cq * 16]     = *(const uint4*)src;
            *(uint4*)&Bs[sm][cq * 16 + 8] = *(const uint4*)(src + 8);
        }
        __syncthreads();
        #pragma unroll
        for (int kk = 0; kk < 64; kk += 32) {
            const int kf = kk + ((lane >> 4) << 3);
            bf16x8 a0 = *(const bf16x8*)&As[wm * 32 + (lane & 15)][kf];
            bf16x8 a1 = *(const bf16x8*)&As[wm * 32 + 16 + (lane & 15)][kf];
            bf16x8 b0 = *(const bf16x8*)&Bs[wn * 32 + (lane & 15)][kf];
            bf16x8 b1 = *(const bf16x8*)&Bs[wn * 32 + 16 + (lane & 15)][kf];
            acc[0][0] = __builtin_amdgcn_mfma_f32_16x16x32_bf16(a0, b0, acc[0][0], 0, 0, 0);
            acc[0][1] = __builtin_amdgcn_mfma_f32_16x16x32_bf16(a0, b1, acc[0][1], 0, 0, 0);
            acc[1][0] = __builtin_amdgcn_mfma_f32_16x16x32_bf16(a1, b0, acc[1][0], 0, 0, 0);
            acc[1][1] = __builtin_amdgcn_mfma_f32_16x16x32_bf16(a1, b1, acc[1][1], 0, 0, 0);
        }
        __syncthreads();
    }
    const int crow = (lane >> 4) << 2;
    const int ccol = lane & 15;
    #pragma unroll
    for (int i = 0; i < 2; ++i) {
        #pragma unroll
        for (int j = 0; j < 2; ++j) {
            const int o = wn * 32 + j * 16 + ccol;
            const float bv = conv_b[o];
            #pragma unroll
            for (int rg = 0; rg < 4; ++rg) {
                const int gr = row0 + wm * 32 + i * 16 + crow + rg;
                const int cn = gr & 3;
                const int pp = gr >> 2;
                const float v = (acc[i][j][rg] + bv) * roi[pp];
                local[(size_t)pp * 320 + cn * 64 + o] = (bf16_t)v;
            }
        }
    }
}

// ---------------------------------------------------------------------------
// graph_feat fill (fallback path only)
// ---------------------------------------------------------------------------
__global__ __launch_bounds__(256) void graph_fill(
    const float* __restrict__ g, bf16_t* __restrict__ local)
{
    const int e = blockIdx.x * 256 + threadIdx.x;
    const int j = e & 63, p = e >> 6;
    const int b = p >> 9, n = p & 511;
    local[(size_t)p * 320 + 256 + j] = (bf16_t)g[((size_t)(b * 64 + j) << 9) + n];
}

// ---------------------------------------------------------------------------
// Generic MFMA GEMM with KSTEP (R11-verified).
// ---------------------------------------------------------------------------
template<int K, int KSTEP, int N, int ACT>
__global__ __launch_bounds__(256) void gemm_bf16(
    const bf16_t* __restrict__ A, const bf16_t* __restrict__ Bt,
    const float* __restrict__ bias, float slope,
    bf16_t* __restrict__ outB, float* __restrict__ outF)
{
    __shared__ bf16_t As[64][KSTEP + 8];
    __shared__ bf16_t Bs[64][KSTEP + 8];
    const int tid = threadIdx.x;
    const int lane = tid & 63;
    const int wave = tid >> 6;
    const int wm = wave & 1, wn = wave >> 1;
    const int row0 = blockIdx.x * 64;
    const int col0 = blockIdx.y * 64;
    const int sm = tid >> 2;
    const int sq = (tid & 3) * (KSTEP / 4);

    f32x4 acc[2][2] = {};
    #pragma unroll 1
    for (int kt = 0; kt < K; kt += KSTEP) {
        {
            const bf16_t* src = A + (size_t)(row0 + sm) * K + kt + sq;
            #pragma unroll
            for (int i = 0; i < KSTEP / 32; ++i)
                *(uint4*)&As[sm][sq + i * 8] = *(const uint4*)(src + i * 8);
        }
        {
            const bf16_t* src = Bt + (size_t)(col0 + sm) * K + kt + sq;
            #pragma unroll
            for (int i = 0; i < KSTEP / 32; ++i)
                *(uint4*)&Bs[sm][sq + i * 8] = *(const uint4*)(src + i * 8);
        }
        __syncthreads();
        #pragma unroll
        for (int kk = 0; kk < KSTEP; kk += 32) {
            const int kf = kk + ((lane >> 4) << 3);
            bf16x8 a0 = *(const bf16x8*)&As[wm * 32 + (lane & 15)][kf];
            bf16x8 a1 = *(const bf16x8*)&As[wm * 32 + 16 + (lane & 15)][kf];
            bf16x8 b0 = *(const bf16x8*)&Bs[wn * 32 + (lane & 15)][kf];
            bf16x8 b1 = *(const bf16x8*)&Bs[wn * 32 + 16 + (lane & 15)][kf];
            acc[0][0] = __builtin_amdgcn_mfma_f32_16x16x32_bf16(a0, b0, acc[0][0], 0, 0, 0);
            acc[0][1] = __builtin_amdgcn_mfma_f32_16x16x32_bf16(a0, b1, acc[0][1], 0, 0, 0);
            acc[1][0] = __builtin_amdgcn_mfma_f32_16x16x32_bf16(a1, b0, acc[1][0], 0, 0, 0);
            acc[1][1] = __builtin_amdgcn_mfma_f32_16x16x32_bf16(a1, b1, acc[1][1], 0, 0, 0);
        }
        __syncthreads();
    }
    const int crow = (lane >> 4) << 2;
    const int ccol = lane & 15;
    #pragma unroll
    for (int i = 0; i < 2; ++i) {
        #pragma unroll
        for (int j = 0; j < 2; ++j) {
            const int gcol = col0 + wn * 32 + j * 16 + ccol;
            const float bv = bias ? bias[gcol] : 0.0f;
            #pragma unroll
            for (int rg = 0; rg < 4; ++rg) {
                const int grow = row0 + wm * 32 + i * 16 + crow + rg;
                float v = acc[i][j][rg] + bv;
                if (ACT == 1) v = v >= 0.0f ? v : slope * v;
                if (outB) outB[(size_t)grow * N + gcol] = (bf16_t)v;
                if (outF) outF[(size_t)grow * N + gcol] = v;
            }
        }
    }
}

// ---------------------------------------------------------------------------
// EdgeConv combine (bf16 AB input)
// ---------------------------------------------------------------------------
__global__ __launch_bounds__(256) void edge_combine(
    const bf16_t* __restrict__ AB, const int* __restrict__ knn,
    const float* __restrict__ gamma, const float* __restrict__ beta,
    const float* __restrict__ mean,  const float* __restrict__ var,
    bf16_t* __restrict__ outB, float* __restrict__ outT)
{
    const int p = blockIdx.x;
    const int b = p >> 9, n = p & 511;
    const int o = threadIdx.x;
    const float sc = gamma[o] / sqrtf(var[o] + 1e-5f);
    const float sh = beta[o] - mean[o] * sc;
    const bf16_t* rowp = AB + (size_t)p * 512;
    const float d = (float)rowp[256 + o] - (float)rowp[o];
    const bf16_t* batch = AB + ((size_t)(b << 9)) * 512;
    float m = -3.4e38f;
    #pragma unroll 4
    for (int k = 0; k < 20; ++k) {
        const int q = knn[n * 20 + k];
        const float v = (float)batch[(size_t)q * 512 + o] + d;
        float y = v * sc + sh;
        y = y >= 0.0f ? y : 0.2f * y;
        m = fmaxf(m, y);
    }
    outB[(size_t)p * 256 + o] = (bf16_t)m;
    if (outT) outT[((size_t)(b * 256 + o) << 9) + n] = m;
}

// ---------------------------------------------------------------------------
// Fused q2+q3: X[8192][256] -> q2(lrelu, LDS) -> bits (d_out).
// 64x64 tile, K=256 single stage, q3 from LDS.
// ---------------------------------------------------------------------------
__global__ __launch_bounds__(256) void q23_kernel(
    const bf16_t* __restrict__ A,      // X [8192][256]
    const bf16_t* __restrict__ B2t,    // wt_q2 [64][256]
    const float* __restrict__ b2,
    const float* __restrict__ w3, const float* __restrict__ b3,
    float* __restrict__ out)
{
    __shared__ bf16_t As[64][264];
    __shared__ bf16_t Bs[64][264];
    __shared__ bf16_t Zs[64][72];
    const int tid = threadIdx.x, lane = tid & 63, wave = tid >> 6;
    const int wm = wave & 1, wn = wave >> 1;
    const int row0 = blockIdx.x * 64;
    const int sm = tid >> 2, sq = (tid & 3) * 64;
    {
        const bf16_t* src = A + (size_t)(row0 + sm) * 256 + sq;
        #pragma unroll
        for (int i = 0; i < 8; ++i)
            *(uint4*)&As[sm][sq + i * 8] = *(const uint4*)(src + i * 8);
    }
    {
        const bf16_t* src = B2t + (size_t)sm * 256 + sq;
        #pragma unroll
        for (int i = 0; i < 8; ++i)
            *(uint4*)&Bs[sm][sq + i * 8] = *(const uint4*)(src + i * 8);
    }
    __syncthreads();
    f32x4 acc[2][2] = {};
    #pragma unroll
    for (int kk = 0; kk < 256; kk += 32) {
        const int kf = kk + ((lane >> 4) << 3);
        bf16x8 a0 = *(const bf16x8*)&As[wm * 32 + (lane & 15)][kf];
        bf16x8 a1 = *(const bf16x8*)&As[wm * 32 + 16 + (lane & 15)][kf];
        bf16x8 b0 = *(const bf16x8*)&Bs[wn * 32 + (lane & 15)][kf];
        bf16x8 b1 = *(const bf16x8*)&Bs[wn * 32 + 16 + (lane & 15)][kf];
        acc[0][0] = __builtin_amdgcn_mfma_f32_16x16x32_bf16(a0, b0, acc[0][0], 0, 0, 0);
        acc[0][1] = __builtin_amdgcn_mfma_f32_16x16x32_bf16(a0, b1, acc[0][1], 0, 0, 0);
        acc[1][0] = __builtin_amdgcn_mfma_f32_16x16x32_bf16(a1, b0, acc[1][0], 0, 0, 0);
        acc[1][1] = __builtin_amdgcn_mfma_f32_16x16x32_bf16(a1, b1, acc[1][1], 0, 0, 0);
    }
    __syncthreads();
    const int crow = (lane >> 4) << 2;
    const int ccol = lane & 15;
    #pragma unroll
    for (int i = 0; i < 2; ++i) {
        #pragma unroll
        for (int j = 0; j < 2; ++j) {
            const int gcol = wn * 32 + j * 16 + ccol;
            const float bv = b2[gcol];
            #pragma unroll
            for (int rg = 0; rg < 4; ++rg) {
                const int rl = wm * 32 + i * 16 + crow + rg;
                float v = acc[i][j][rg] + bv;
                v = v >= 0.0f ? v : 0.01f * v;
                Zs[rl][gcol] = (bf16_t)v;
            }
        }
    }
    __syncthreads();
    if (tid < 128) {
        const int rl = tid >> 1, jj = tid & 1;
        float s = b3[jj];
        #pragma unroll
        for (int c = 0; c < 64; ++c)
            s += (float)Zs[rl][c] * w3[2 * c + jj];
        const int gr = row0 + rl, bb = gr >> 9, nn = gr & 511;
        out[(size_t)(bb * 2 + jj) * 512 + nn] = s;
    }
}

// ---------------------------------------------------------------------------
// Head final layer (fallback path only)
// ---------------------------------------------------------------------------
__global__ __launch_bounds__(256) void q3_kernel(
    const bf16_t* __restrict__ Z, const float* __restrict__ w3,
    const float* __restrict__ b3, float* __restrict__ out)
{
    const int p = blockIdx.x * 256 + threadIdx.x;
    const int b = p >> 9, n = p & 511;
    const bf16_t* q = Z + (size_t)p * 64;
    float s0 = b3[0], s1 = b3[1];
    #pragma unroll
    for (int c = 0; c < 64; ++c) {
        const float v = (float)q[c];
        s0 += v * w3[2 * c];
        s1 += v * w3[2 * c + 1];
    }
    out[(size_t)(b * 2 + 0) * 512 + n] = s0;
    out[(size_t)(b * 2 + 1) * 512 + n] = s1;
}

// ---------------------------------------------------------------------------
extern "C" void kernel_launch(void* const* d_in, const int* in_sizes, int n_in,
                              void* d_out, int out_size, void* d_ws, size_t ws_size,
                              hipStream_t stream)
{
    const float* img      = (const float*)d_in[0];
    const float* graph    = (const float*)d_in[1];
    const float* roi      = (const float*)d_in[2];
    const int*   px       = (const int*)d_in[3];
    const int*   py       = (const int*)d_in[4];
    const int*   knn      = (const int*)d_in[5];
    const float* conv_w   = (const float*)d_in[6];
    const float* conv_b   = (const float*)d_in[7];
    const float* pre_w1   = (const float*)d_in[8];
    const float* pre_b1   = (const float*)d_in[9];
    const float* pre_w2   = (const float*)d_in[10];
    const float* pre_b2   = (const float*)d_in[11];
    const float* g1_w     = (const float*)d_in[12];
    const float* g1_gamma = (const float*)d_in[13];
    const float* g1_beta  = (const float*)d_in[14];
    const float* g1_mean  = (const float*)d_in[15];
    const float* g1_var   = (const float*)d_in[16];
    const float* g2_w     = (const float*)d_in[17];
    const float* g2_gamma = (const float*)d_in[18];
    const float* g2_beta  = (const float*)d_in[19];
    const float* g2_mean  = (const float*)d_in[20];
    const float* g2_var   = (const float*)d_in[21];
    const float* q_w1     = (const float*)d_in[22];
    const float* q_b1     = (const float*)d_in[23];
    const float* q_w2     = (const float*)d_in[24];
    const float* q_b2     = (const float*)d_in[25];
    const float* q_w3     = (const float*)d_in[26];
    const float* q_b3     = (const float*)d_in[27];
    float* out = (float*)d_out;

    if (ws_size < WS_BASE) return;

    char* ws = (char*)d_ws;
    bf16_t* wt_conv  = (bf16_t*)(ws + OFF_WCONV_OLD);
    bf16_t* wt_convp = (bf16_t*)(ws + OFF_WCONVP);
    bf16_t* wt_pre1  = (bf16_t*)(ws + OFF_WPRE1);
    bf16_t* wt_pre2  = (bf16_t*)(ws + OFF_WPRE2);
    bf16_t* wt_ec1   = (bf16_t*)(ws + OFF_WEC1);
    bf16_t* wt_ec2   = (bf16_t*)(ws + OFF_WEC2);
    bf16_t* wt_q1    = (bf16_t*)(ws + OFF_WQ1);
    bf16_t* wt_q2    = (bf16_t*)(ws + OFF_WQ2);
    bf16_t* local    = (bf16_t*)(ws + OFF_LOCAL);
    bf16_t* X        = (bf16_t*)(ws + OFF_X);
    bf16_t* Y        = (bf16_t*)(ws + OFF_Y);
    bf16_t* Z        = (bf16_t*)(ws + OFF_Z);
    bf16_t* AB       = (bf16_t*)(ws + OFF_UNION);
    bf16_t* imgT     = (bf16_t*)(ws + OFF_UNION);

    const bool big = ws_size >= WS_FULL;

    wprep_pad_kernel<<<(WP_TOTAL + PAD_THREADS + 255) / 256, 256, 0, stream>>>(
        conv_w, pre_w1, pre_w2, g1_w, g2_w, q_w1, q_w2,
        wt_conv, wt_convp, wt_pre1, wt_pre2, wt_ec1, wt_ec2, wt_q1, wt_q2,
        big ? imgT : nullptr);

    if (big) {
        // 2 batch-groups: conv reads imgT while its group is L3-resident
        for (int g = 0; g < 2; ++g) {
            transpose_img<<<8 * 128 * 2 * 4, 256, 0, stream>>>(img, imgT, 8 * g);
            conv_gather_gemm3p<<<CONVM / 32 / 2, 256, 0, stream>>>(
                imgT, wt_convp, conv_b, roi, px, py, graph, local, g * (CONVM / 2));
        }
    } else {
        conv_gather_gemm<<<CONVM / 64, 256, 0, stream>>>(
            img, wt_conv, conv_b, roi, px, py, local);
        graph_fill<<<(PTS * 64) / 256, 256, 0, stream>>>(graph, local);
    }

    gemm_bf16<320, 160, 256, 1><<<dim3(PTS / 64, 4), 256, 0, stream>>>(
        local, wt_pre1, pre_b1, 0.01f, X, nullptr);
    gemm_bf16<256, 256, 256, 1><<<dim3(PTS / 64, 4), 256, 0, stream>>>(
        X, wt_pre2, pre_b2, 0.01f, Y, nullptr);

    gemm_bf16<256, 128, 512, 0><<<dim3(PTS / 64, 8), 256, 0, stream>>>(
        Y, wt_ec1, nullptr, 0.0f, AB, nullptr);
    edge_combine<<<PTS, 256, 0, stream>>>(
        AB, knn, g1_gamma, g1_beta, g1_mean, g1_var, X, nullptr);

    gemm_bf16<256, 128, 512, 0><<<dim3(PTS / 64, 8), 256, 0, stream>>>(
        X, wt_ec2, nullptr, 0.0f, AB, nullptr);
    edge_combine<<<PTS, 256, 0, stream>>>(
        AB, knn, g2_gamma, g2_beta, g2_mean, g2_var, Y, out + 16384);

    gemm_bf16<256, 256, 256, 1><<<dim3(PTS / 64, 4), 256, 0, stream>>>(
        Y, wt_q1, q_b1, 0.01f, X, nullptr);
    q23_kernel<<<PTS / 64, 256, 0, stream>>>(
        X, wt_q2, q_b2, q_w3, q_b3, out);
}